// Round 1
// baseline (915.708 us; speedup 1.0000x reference)
//
#include <hip/hip_runtime.h>
#include <cstdint>

static constexpr float kEps  = 1e-5f;
static constexpr float kBeta = 0.1f;

__device__ __forceinline__ float wredsum(float v){
  #pragma unroll
  for(int o=1;o<64;o<<=1) v += __shfl_xor(v,o);
  return v;
}
__device__ __forceinline__ float wredmax(float v){
  #pragma unroll
  for(int o=1;o<64;o<<=1) v = fmaxf(v,__shfl_xor(v,o));
  return v;
}

// ---------------- CSR build ----------------
__global__ void k_hist(const int* __restrict__ row, int* __restrict__ deg, int E){
  int e = blockIdx.x*256 + threadIdx.x;
  if (e < E) atomicAdd(&deg[row[e]], 1);
}

__global__ void k_scan_block(const int* __restrict__ deg, int* __restrict__ start,
                             int* __restrict__ bsum, int N){
  __shared__ int s[256];
  int t = threadIdx.x;
  int i = blockIdx.x*256 + t;
  int v = (i < N) ? deg[i] : 0;
  s[t] = v; __syncthreads();
  for (int off=1; off<256; off<<=1){
    int add = (t >= off) ? s[t-off] : 0;
    __syncthreads();
    s[t] += add;
    __syncthreads();
  }
  if (i < N) start[i+1] = s[t];
  if (t == 255) bsum[blockIdx.x] = s[255];
}

__global__ void k_scan_bsum(const int* __restrict__ bsum, int* __restrict__ boff, int nb){
  __shared__ int s[256];
  int t = threadIdx.x;
  int v = (t < nb) ? bsum[t] : 0;
  s[t] = v; __syncthreads();
  for (int off=1; off<256; off<<=1){
    int add = (t >= off) ? s[t-off] : 0;
    __syncthreads();
    s[t] += add;
    __syncthreads();
  }
  if (t < nb) boff[t] = s[t] - v;   // exclusive
}

__global__ void k_scan_add(int* __restrict__ start, const int* __restrict__ boff, int N){
  int i = blockIdx.x*256 + threadIdx.x;
  if (i < N) start[i+1] += boff[blockIdx.x];
  if (blockIdx.x==0 && threadIdx.x==0) start[0] = 0;
}

__global__ void k_fill(const int* __restrict__ row, const int* __restrict__ col,
                       const int* __restrict__ start, int* __restrict__ cursor,
                       int* __restrict__ ecsr, int* __restrict__ colcsr, int E){
  int e = blockIdx.x*256 + threadIdx.x;
  if (e < E){
    int r = row[e];
    int pos = atomicAdd(&cursor[r], 1);
    int i = start[r] + pos;
    ecsr[i] = e;
    colcsr[i] = col[e];
  }
}

// ---------------- GEMM1: x@W1 + b1 (raw, relu/LN later) ----------------
// block = 256 threads (j = output col), 16 nodes per block.
__global__ __launch_bounds__(256) void k_gemm1(const float* __restrict__ x,
    const float* __restrict__ W1, const float* __restrict__ b1,
    float* __restrict__ out){
  int j = threadIdx.x;
  int n0 = blockIdx.x * 16;
  float acc[16];
  #pragma unroll
  for (int m=0;m<16;m++) acc[m]=0.f;
  const float* xb = x + (size_t)n0*256;
  for (int k=0;k<256;k+=4){
    float w0 = W1[(k+0)*256 + j];
    float w1 = W1[(k+1)*256 + j];
    float w2 = W1[(k+2)*256 + j];
    float w3 = W1[(k+3)*256 + j];
    #pragma unroll
    for (int m=0;m<16;m++){
      float4 xv = *reinterpret_cast<const float4*>(xb + m*256 + k);  // wave-uniform -> s_load
      acc[m] = fmaf(xv.x, w0, acc[m]);
      acc[m] = fmaf(xv.y, w1, acc[m]);
      acc[m] = fmaf(xv.z, w2, acc[m]);
      acc[m] = fmaf(xv.w, w3, acc[m]);
    }
  }
  float bias = b1[j];
  #pragma unroll
  for (int m=0;m<16;m++) out[(size_t)(n0+m)*256 + j] = acc[m] + bias;
}

// ---------------- relu + LN, write ego and x ----------------
__global__ __launch_bounds__(256) void k_ln0(const float* __restrict__ xin,
    const float* __restrict__ g, const float* __restrict__ b,
    float* __restrict__ ego, float* __restrict__ xout, int N){
  int lane = threadIdx.x & 63;
  int n = blockIdx.x*4 + (threadIdx.x >> 6);
  if (n >= N) return;
  const float* xr = xin + (size_t)n*256;
  float v0 = fmaxf(xr[      lane], 0.f);
  float v1 = fmaxf(xr[ 64 + lane], 0.f);
  float v2 = fmaxf(xr[128 + lane], 0.f);
  float v3 = fmaxf(xr[192 + lane], 0.f);
  float mu = wredsum(v0+v1+v2+v3) * (1.f/256.f);
  float d0=v0-mu, d1=v1-mu, d2=v2-mu, d3=v3-mu;
  float var = wredsum(d0*d0+d1*d1+d2*d2+d3*d3) * (1.f/256.f);
  float inv = rsqrtf(var + kEps);
  float y0 = d0*inv*g[      lane] + b[      lane];
  float y1 = d1*inv*g[ 64 + lane] + b[ 64 + lane];
  float y2 = d2*inv*g[128 + lane] + b[128 + lane];
  float y3 = d3*inv*g[192 + lane] + b[192 + lane];
  size_t base = (size_t)n*256;
  ego[base +       lane] = y0; xout[base +       lane] = y0;
  ego[base +  64 + lane] = y1; xout[base +  64 + lane] = y1;
  ego[base + 128 + lane] = y2; xout[base + 128 + lane] = y2;
  ego[base + 192 + lane] = y3; xout[base + 192 + lane] = y3;
}

// ---------------- h = x @ lin_w  [256 -> 64] ----------------
// block 256: 4 waves, each wave handles 8 nodes, lane = out col j.
__global__ __launch_bounds__(256) void k_gemm_h(const float* __restrict__ x,
    const float* __restrict__ W, float* __restrict__ h, int N){
  int j = threadIdx.x & 63;
  int q = threadIdx.x >> 6;
  int n0 = blockIdx.x*32 + q*8;
  if (n0 >= N) return;
  float acc[8];
  #pragma unroll
  for (int m=0;m<8;m++) acc[m]=0.f;
  const float* xb = x + (size_t)n0*256;
  for (int k=0;k<256;k+=4){
    float w0 = W[(k+0)*64 + j];
    float w1 = W[(k+1)*64 + j];
    float w2 = W[(k+2)*64 + j];
    float w3 = W[(k+3)*64 + j];
    #pragma unroll
    for (int m=0;m<8;m++){
      float4 xv = *reinterpret_cast<const float4*>(xb + m*256 + k);  // uniform -> s_load
      acc[m] = fmaf(xv.x,w0,fmaf(xv.y,w1,fmaf(xv.z,w2,fmaf(xv.w,w3,acc[m]))));
    }
  }
  #pragma unroll
  for (int m=0;m<8;m++) h[(size_t)(n0+m)*64 + j] = acc[m];
}

// ---------------- edge attention: a[e] = softmax(relu(0.5 h_row + h_col) @ att) ----------------
// 16 lanes per edge, 16 edges per block.
__global__ __launch_bounds__(256) void k_edge(const float* __restrict__ h,
    const int* __restrict__ row, const int* __restrict__ col,
    const float* __restrict__ attw, float4* __restrict__ a_out, int E){
  int t = threadIdx.x;
  int g = t >> 4, l = t & 15;
  int e = blockIdx.x*16 + g;
  if (e >= E) return;
  int r = row[e], c = col[e];
  float4 hr = *reinterpret_cast<const float4*>(h + (size_t)r*64 + l*4);
  float4 hc = *reinterpret_cast<const float4*>(h + (size_t)c*64 + l*4);
  float p0 = fmaxf(0.5f*hr.x + hc.x, 0.f);
  float p1 = fmaxf(0.5f*hr.y + hc.y, 0.f);
  float p2 = fmaxf(0.5f*hr.z + hc.z, 0.f);
  float p3 = fmaxf(0.5f*hr.w + hc.w, 0.f);
  float4 t0 = *reinterpret_cast<const float4*>(attw + (l*4+0)*4);
  float4 t1 = *reinterpret_cast<const float4*>(attw + (l*4+1)*4);
  float4 t2 = *reinterpret_cast<const float4*>(attw + (l*4+2)*4);
  float4 t3 = *reinterpret_cast<const float4*>(attw + (l*4+3)*4);
  float c0 = p0*t0.x + p1*t1.x + p2*t2.x + p3*t3.x;
  float c1 = p0*t0.y + p1*t1.y + p2*t2.y + p3*t3.y;
  float c2 = p0*t0.z + p1*t1.z + p2*t2.z + p3*t3.z;
  float c3 = p0*t0.w + p1*t1.w + p2*t2.w + p3*t3.w;
  #pragma unroll
  for (int off=1; off<16; off<<=1){
    c0 += __shfl_xor(c0, off);
    c1 += __shfl_xor(c1, off);
    c2 += __shfl_xor(c2, off);
    c3 += __shfl_xor(c3, off);
  }
  if (l == 0){
    float m = fmaxf(fmaxf(c0,c1), fmaxf(c2,c3));
    float e0 = __expf(c0-m), e1 = __expf(c1-m), e2 = __expf(c2-m), e3 = __expf(c3-m);
    float invs = 1.f/(e0+e1+e2+e3);
    a_out[e] = make_float4(e0*invs, e1*invs, e2*invs, e3*invs);
  }
}

// ---------------- aggregate + relu + LN + residual blend ----------------
// one wave per node, lane = feature dim within HID.
__global__ __launch_bounds__(256) void k_agg(const float* __restrict__ h,
    const int* __restrict__ ecsr, const int* __restrict__ colcsr,
    const float4* __restrict__ aws, const int* __restrict__ start,
    const float* __restrict__ ego, const float* __restrict__ g, const float* __restrict__ b,
    float* __restrict__ xout, int N){
  int lane = threadIdx.x & 63;
  int n = blockIdx.x*4 + (threadIdx.x >> 6);
  if (n >= N) return;
  int s0 = start[n], s1 = start[n+1];
  float a0=0.f, a1=0.f, a2=0.f, a3=0.f;
  for (int i=s0; i<s1; ++i){
    int e = ecsr[i];          // wave-uniform -> scalar load
    int c = colcsr[i];        // wave-uniform -> scalar load
    float4 aa = aws[e];       // wave-uniform -> scalar load
    float hv = h[(size_t)c*64 + lane];
    a0 = fmaf(aa.x, hv, a0);
    a1 = fmaf(aa.y, hv, a1);
    a2 = fmaf(aa.z, hv, a2);
    a3 = fmaf(aa.w, hv, a3);
  }
  float v0 = fmaxf(a0,0.f), v1 = fmaxf(a1,0.f), v2 = fmaxf(a2,0.f), v3 = fmaxf(a3,0.f);
  float mu = wredsum(v0+v1+v2+v3) * (1.f/256.f);
  float d0=v0-mu, d1=v1-mu, d2=v2-mu, d3=v3-mu;
  float var = wredsum(d0*d0+d1*d1+d2*d2+d3*d3) * (1.f/256.f);
  float inv = rsqrtf(var + kEps);
  size_t base = (size_t)n*256;
  float y0 = d0*inv*g[      lane] + b[      lane];
  float y1 = d1*inv*g[ 64 + lane] + b[ 64 + lane];
  float y2 = d2*inv*g[128 + lane] + b[128 + lane];
  float y3 = d3*inv*g[192 + lane] + b[192 + lane];
  xout[base +       lane] = (1.f-kBeta)*y0 + kBeta*ego[base +       lane];
  xout[base +  64 + lane] = (1.f-kBeta)*y1 + kBeta*ego[base +  64 + lane];
  xout[base + 128 + lane] = (1.f-kBeta)*y2 + kBeta*ego[base + 128 + lane];
  xout[base + 192 + lane] = (1.f-kBeta)*y3 + kBeta*ego[base + 192 + lane];
}

// ---------------- logits = x@W2 + b2 ; log_softmax ----------------
__global__ __launch_bounds__(256) void k_out(const float* __restrict__ x,
    const float* __restrict__ W2, const float* __restrict__ b2,
    float* __restrict__ out, int N){
  int j = threadIdx.x & 63;
  int q = threadIdx.x >> 6;
  int n0 = blockIdx.x*32 + q*8;
  if (n0 >= N) return;
  float acc[8];
  #pragma unroll
  for (int m=0;m<8;m++) acc[m]=0.f;
  const float* xb = x + (size_t)n0*256;
  for (int k=0;k<256;k+=4){
    float w0 = W2[(k+0)*64 + j];
    float w1 = W2[(k+1)*64 + j];
    float w2 = W2[(k+2)*64 + j];
    float w3 = W2[(k+3)*64 + j];
    #pragma unroll
    for (int m=0;m<8;m++){
      float4 xv = *reinterpret_cast<const float4*>(xb + m*256 + k);  // uniform -> s_load
      acc[m] = fmaf(xv.x,w0,fmaf(xv.y,w1,fmaf(xv.z,w2,fmaf(xv.w,w3,acc[m]))));
    }
  }
  float bias = b2[j];
  #pragma unroll
  for (int m=0;m<8;m++){
    float l = acc[m] + bias;
    float mx = wredmax(l);
    float s  = wredsum(__expf(l-mx));
    out[(size_t)(n0+m)*64 + j] = (l-mx) - __logf(s);
  }
}

extern "C" void kernel_launch(void* const* d_in, const int* in_sizes, int n_in,
                              void* d_out, int out_size, void* d_ws, size_t ws_size,
                              hipStream_t stream){
  const float* x_in = (const float*)d_in[0];
  const int*   ei   = (const int*)d_in[1];
  const float* W1   = (const float*)d_in[2];
  const float* b1   = (const float*)d_in[3];
  const float* lin  = (const float*)d_in[4];
  const float* att  = (const float*)d_in[5];
  const float* lng  = (const float*)d_in[6];
  const float* lnb  = (const float*)d_in[7];
  const float* W2   = (const float*)d_in[8];
  const float* b2   = (const float*)d_in[9];
  float* out = (float*)d_out;

  const int N = in_sizes[0] / 256;   // 50000
  const int E = in_sizes[1] / 2;     // 800000
  const int* row = ei;
  const int* col = ei + E;

  char* basep = (char*)d_ws;
  size_t off = 0;
  auto alloc = [&](size_t bytes)->char*{
    char* p = basep + off;
    off += (bytes + 255) & ~(size_t)255;
    return p;
  };
  float*  ego    = (float*) alloc((size_t)N*256*4);
  float*  xbuf   = (float*) alloc((size_t)N*256*4);
  float*  hbuf   = (float*) alloc((size_t)N*64*4);
  float4* aws    = (float4*)alloc((size_t)E*16);
  int*    startp = (int*)   alloc((size_t)(N+1)*4);
  int*    deg    = (int*)   alloc((size_t)N*4);   // also reused as cursor
  int*    ecsr   = (int*)   alloc((size_t)E*4);
  int*    colcsr = (int*)   alloc((size_t)E*4);
  int*    bsum   = (int*)   alloc(256*4);
  int*    boff   = (int*)   alloc(256*4);

  int nbE = (E + 255)/256;   // 3125
  int nbN = (N + 255)/256;   // 196

  // CSR build
  hipMemsetAsync(deg, 0, (size_t)N*4, stream);
  k_hist<<<nbE,256,0,stream>>>(row, deg, E);
  k_scan_block<<<nbN,256,0,stream>>>(deg, startp, bsum, N);
  k_scan_bsum<<<1,256,0,stream>>>(bsum, boff, nbN);
  k_scan_add<<<nbN,256,0,stream>>>(startp, boff, N);
  hipMemsetAsync(deg, 0, (size_t)N*4, stream);     // cursor
  k_fill<<<nbE,256,0,stream>>>(row, col, startp, deg, ecsr, colcsr, E);

  // input projection + LN -> ego, x
  k_gemm1<<<N/16,256,0,stream>>>(x_in, W1, b1, xbuf);
  k_ln0<<<(N+3)/4,256,0,stream>>>(xbuf, lng, lnb, ego, xbuf, N);

  for (int L=0; L<2; ++L){
    k_gemm_h<<<(N+31)/32,256,0,stream>>>(xbuf, lin + (size_t)L*256*64, hbuf, N);
    k_edge<<<(E+15)/16,256,0,stream>>>(hbuf, row, col, att + (size_t)L*64*4, aws, E);
    k_agg<<<(N+3)/4,256,0,stream>>>(hbuf, ecsr, colcsr, aws, startp, ego,
                                    lng + (size_t)(L+1)*256, lnb + (size_t)(L+1)*256,
                                    xbuf, N);
  }
  k_out<<<(N+31)/32,256,0,stream>>>(xbuf, W2, b2, out, N);
}

// Round 2
// 705.850 us; speedup vs baseline: 1.2973x; 1.2973x over previous
//
#include <hip/hip_runtime.h>
#include <cstdint>

static constexpr float kEps  = 1e-5f;
static constexpr float kBeta = 0.1f;

__device__ __forceinline__ float wredsum(float v){
  #pragma unroll
  for(int o=1;o<64;o<<=1) v += __shfl_xor(v,o);
  return v;
}
__device__ __forceinline__ float wredmax(float v){
  #pragma unroll
  for(int o=1;o<64;o<<=1) v = fmaxf(v,__shfl_xor(v,o));
  return v;
}

// ---------------- CSR build ----------------
__global__ void k_hist(const int* __restrict__ row, int* __restrict__ deg, int E){
  int e = blockIdx.x*256 + threadIdx.x;
  if (e < E) atomicAdd(&deg[row[e]], 1);
}

__global__ void k_scan_block(const int* __restrict__ deg, int* __restrict__ start,
                             int* __restrict__ bsum, int N){
  __shared__ int s[256];
  int t = threadIdx.x;
  int i = blockIdx.x*256 + t;
  int v = (i < N) ? deg[i] : 0;
  s[t] = v; __syncthreads();
  for (int off=1; off<256; off<<=1){
    int add = (t >= off) ? s[t-off] : 0;
    __syncthreads();
    s[t] += add;
    __syncthreads();
  }
  if (i < N) start[i+1] = s[t];
  if (t == 255) bsum[blockIdx.x] = s[255];
}

__global__ void k_scan_bsum(const int* __restrict__ bsum, int* __restrict__ boff, int nb){
  __shared__ int s[256];
  int t = threadIdx.x;
  int v = (t < nb) ? bsum[t] : 0;
  s[t] = v; __syncthreads();
  for (int off=1; off<256; off<<=1){
    int add = (t >= off) ? s[t-off] : 0;
    __syncthreads();
    s[t] += add;
    __syncthreads();
  }
  if (t < nb) boff[t] = s[t] - v;   // exclusive
}

__global__ void k_scan_add(int* __restrict__ start, const int* __restrict__ boff, int N){
  int i = blockIdx.x*256 + threadIdx.x;
  if (i < N) start[i+1] += boff[blockIdx.x];
  if (blockIdx.x==0 && threadIdx.x==0) start[0] = 0;
}

__global__ void k_fill(const int* __restrict__ row, const int* __restrict__ col,
                       const int* __restrict__ start, int* __restrict__ cursor,
                       int* __restrict__ ecsr, int* __restrict__ colcsr, int E){
  int e = blockIdx.x*256 + threadIdx.x;
  if (e < E){
    int r = row[e];
    int pos = atomicAdd(&cursor[r], 1);
    int i = start[r] + pos;
    ecsr[i] = e;
    colcsr[i] = col[e];
  }
}

// ---------------- GEMM1 + bias + relu + LN, write ego and x ----------------
// Tile: 64 nodes x 256 cols, K in 8 chunks of 32. 256 threads.
// Thread (ta=tid>>5, tb=tid&31): nodes m0=ta*8..+7, cols {tb+32u, u=0..7}.
// xs reads are wave-broadcast; ws reads hit bank (4k+tb)%32 -> conflict-free.
__global__ __launch_bounds__(256) void k_gemm1_ln(const float* __restrict__ x,
    const float* __restrict__ W1, const float* __restrict__ b1,
    const float* __restrict__ g, const float* __restrict__ bb,
    float* __restrict__ ego, float* __restrict__ xout, int N){
  __shared__ float xs[64][36];
  __shared__ float ws[32][260];
  const int tid = threadIdx.x;
  const int n0 = blockIdx.x * 64;
  const int m0 = (tid >> 5) * 8;
  const int jb = tid & 31;
  // staging maps
  const int xr  = tid >> 3;          // 0..31
  const int xc  = (tid & 7) * 4;     // 0..28
  const int wj  = (tid & 63) * 4;    // 0..252
  const int wk0 = tid >> 6;          // 0..3

  float acc[8][8];
  #pragma unroll
  for (int i=0;i<8;i++)
    #pragma unroll
    for (int u=0;u<8;u++) acc[i][u]=0.f;

  for (int kc=0; kc<8; ++kc){
    int gr0 = min(n0 + xr,      N-1);
    int gr1 = min(n0 + xr + 32, N-1);
    float4 a0 = *reinterpret_cast<const float4*>(&x[(size_t)gr0*256 + kc*32 + xc]);
    float4 a1 = *reinterpret_cast<const float4*>(&x[(size_t)gr1*256 + kc*32 + xc]);
    *reinterpret_cast<float4*>(&xs[xr     ][xc]) = a0;
    *reinterpret_cast<float4*>(&xs[xr + 32][xc]) = a1;
    #pragma unroll
    for (int s=0;s<8;s++){
      int kr = wk0 + s*4;
      float4 w4 = *reinterpret_cast<const float4*>(&W1[(size_t)(kc*32+kr)*256 + wj]);
      *reinterpret_cast<float4*>(&ws[kr][wj]) = w4;
    }
    __syncthreads();
    #pragma unroll 8
    for (int k=0;k<32;++k){
      float xv[8], wv[8];
      #pragma unroll
      for (int i=0;i<8;i++) xv[i] = xs[m0+i][k];
      #pragma unroll
      for (int u=0;u<8;u++) wv[u] = ws[k][jb + 32*u];
      #pragma unroll
      for (int i=0;i<8;i++)
        #pragma unroll
        for (int u=0;u<8;u++)
          acc[i][u] = fmaf(xv[i], wv[u], acc[i][u]);
    }
    __syncthreads();
  }

  // epilogue: bias + relu + LN (reduce across the 32 tb-lanes) + store ego,x
  float b1v[8], gv[8], bbv[8];
  #pragma unroll
  for (int u=0;u<8;u++){
    int j = jb + 32*u;
    b1v[u] = b1[j]; gv[u] = g[j]; bbv[u] = bb[j];
  }
  #pragma unroll
  for (int i=0;i<8;i++){
    float s=0.f, sq=0.f;
    #pragma unroll
    for (int u=0;u<8;u++){
      float v = fmaxf(acc[i][u] + b1v[u], 0.f);
      acc[i][u] = v;
      s += v; sq += v*v;
    }
    #pragma unroll
    for (int o=1;o<32;o<<=1){ s += __shfl_xor(s,o); sq += __shfl_xor(sq,o); }
    int m = n0 + m0 + i;
    if (m < N){
      float mu  = s * (1.f/256.f);
      float var = sq * (1.f/256.f) - mu*mu;
      float inv = rsqrtf(fmaxf(var, 0.f) + kEps);
      size_t base = (size_t)m*256;
      #pragma unroll
      for (int u=0;u<8;u++){
        float y = (acc[i][u]-mu)*inv*gv[u] + bbv[u];
        ego[base + jb + 32*u]  = y;
        xout[base + jb + 32*u] = y;
      }
    }
  }
}

// ---------------- h = x @ lin_w  [256 -> 64], LDS-tiled ----------------
// Tile: 64 nodes x 64 cols, K in 4 chunks of 64. 256 threads.
// Thread (ta=tid>>4, tb=tid&15): nodes ta*4..+3, cols tb*4..+3.
__global__ __launch_bounds__(256) void k_hgemm(const float* __restrict__ x,
    const float* __restrict__ W, float* __restrict__ h, int N){
  __shared__ float xs[64][68];
  __shared__ float ws[64][68];
  const int tid = threadIdx.x;
  const int n0 = blockIdx.x * 64;
  const int ta = tid >> 4;
  const int tb = tid & 15;
  const int sr  = tid >> 2;        // 0..63
  const int sc0 = (tid & 3) * 4;   // 0..12

  float acc[4][4];
  #pragma unroll
  for (int i=0;i<4;i++)
    #pragma unroll
    for (int q=0;q<4;q++) acc[i][q]=0.f;

  for (int kc=0; kc<4; ++kc){
    int gr = min(n0 + sr, N-1);
    #pragma unroll
    for (int s=0;s<4;s++){
      int c = sc0 + s*16;
      *reinterpret_cast<float4*>(&xs[sr][c]) =
          *reinterpret_cast<const float4*>(&x[(size_t)gr*256 + kc*64 + c]);
      *reinterpret_cast<float4*>(&ws[sr][c]) =
          *reinterpret_cast<const float4*>(&W[(size_t)(kc*64+sr)*64 + c]);
    }
    __syncthreads();
    #pragma unroll 4
    for (int k=0;k<64;++k){
      float xv[4], wv[4];
      #pragma unroll
      for (int i=0;i<4;i++) xv[i] = xs[ta*4+i][k];
      #pragma unroll
      for (int q=0;q<4;q++) wv[q] = ws[k][tb*4+q];
      #pragma unroll
      for (int i=0;i<4;i++)
        #pragma unroll
        for (int q=0;q<4;q++)
          acc[i][q] = fmaf(xv[i], wv[q], acc[i][q]);
    }
    __syncthreads();
  }
  #pragma unroll
  for (int i=0;i<4;i++){
    int m = n0 + ta*4 + i;
    if (m < N){
      #pragma unroll
      for (int q=0;q<4;q++) h[(size_t)m*64 + tb*4 + q] = acc[i][q];
    }
  }
}

// ---------------- edge attention: a[e] = softmax(relu(0.5 h_row + h_col) @ att) ----------------
__global__ __launch_bounds__(256) void k_edge(const float* __restrict__ h,
    const int* __restrict__ row, const int* __restrict__ col,
    const float* __restrict__ attw, float4* __restrict__ a_out, int E){
  int t = threadIdx.x;
  int g = t >> 4, l = t & 15;
  int e = blockIdx.x*16 + g;
  if (e >= E) return;
  int r = row[e], c = col[e];
  float4 hr = *reinterpret_cast<const float4*>(h + (size_t)r*64 + l*4);
  float4 hc = *reinterpret_cast<const float4*>(h + (size_t)c*64 + l*4);
  float p0 = fmaxf(0.5f*hr.x + hc.x, 0.f);
  float p1 = fmaxf(0.5f*hr.y + hc.y, 0.f);
  float p2 = fmaxf(0.5f*hr.z + hc.z, 0.f);
  float p3 = fmaxf(0.5f*hr.w + hc.w, 0.f);
  float4 t0 = *reinterpret_cast<const float4*>(attw + (l*4+0)*4);
  float4 t1 = *reinterpret_cast<const float4*>(attw + (l*4+1)*4);
  float4 t2 = *reinterpret_cast<const float4*>(attw + (l*4+2)*4);
  float4 t3 = *reinterpret_cast<const float4*>(attw + (l*4+3)*4);
  float c0 = p0*t0.x + p1*t1.x + p2*t2.x + p3*t3.x;
  float c1 = p0*t0.y + p1*t1.y + p2*t2.y + p3*t3.y;
  float c2 = p0*t0.z + p1*t1.z + p2*t2.z + p3*t3.z;
  float c3 = p0*t0.w + p1*t1.w + p2*t2.w + p3*t3.w;
  #pragma unroll
  for (int off=1; off<16; off<<=1){
    c0 += __shfl_xor(c0, off);
    c1 += __shfl_xor(c1, off);
    c2 += __shfl_xor(c2, off);
    c3 += __shfl_xor(c3, off);
  }
  if (l == 0){
    float m = fmaxf(fmaxf(c0,c1), fmaxf(c2,c3));
    float e0 = __expf(c0-m), e1 = __expf(c1-m), e2 = __expf(c2-m), e3 = __expf(c3-m);
    float invs = 1.f/(e0+e1+e2+e3);
    a_out[e] = make_float4(e0*invs, e1*invs, e2*invs, e3*invs);
  }
}

// ---------------- aggregate + relu + LN + residual blend ----------------
__global__ __launch_bounds__(256) void k_agg(const float* __restrict__ h,
    const int* __restrict__ ecsr, const int* __restrict__ colcsr,
    const float4* __restrict__ aws, const int* __restrict__ start,
    const float* __restrict__ ego, const float* __restrict__ g, const float* __restrict__ b,
    float* __restrict__ xout, int N){
  int lane = threadIdx.x & 63;
  int n = blockIdx.x*4 + (threadIdx.x >> 6);
  if (n >= N) return;
  int s0 = start[n], s1 = start[n+1];
  float a0=0.f, a1=0.f, a2=0.f, a3=0.f;
  for (int i=s0; i<s1; ++i){
    int e = ecsr[i];
    int c = colcsr[i];
    float4 aa = aws[e];
    float hv = h[(size_t)c*64 + lane];
    a0 = fmaf(aa.x, hv, a0);
    a1 = fmaf(aa.y, hv, a1);
    a2 = fmaf(aa.z, hv, a2);
    a3 = fmaf(aa.w, hv, a3);
  }
  float v0 = fmaxf(a0,0.f), v1 = fmaxf(a1,0.f), v2 = fmaxf(a2,0.f), v3 = fmaxf(a3,0.f);
  float mu = wredsum(v0+v1+v2+v3) * (1.f/256.f);
  float d0=v0-mu, d1=v1-mu, d2=v2-mu, d3=v3-mu;
  float var = wredsum(d0*d0+d1*d1+d2*d2+d3*d3) * (1.f/256.f);
  float inv = rsqrtf(var + kEps);
  size_t base = (size_t)n*256;
  float y0 = d0*inv*g[      lane] + b[      lane];
  float y1 = d1*inv*g[ 64 + lane] + b[ 64 + lane];
  float y2 = d2*inv*g[128 + lane] + b[128 + lane];
  float y3 = d3*inv*g[192 + lane] + b[192 + lane];
  xout[base +       lane] = (1.f-kBeta)*y0 + kBeta*ego[base +       lane];
  xout[base +  64 + lane] = (1.f-kBeta)*y1 + kBeta*ego[base +  64 + lane];
  xout[base + 128 + lane] = (1.f-kBeta)*y2 + kBeta*ego[base + 128 + lane];
  xout[base + 192 + lane] = (1.f-kBeta)*y3 + kBeta*ego[base + 192 + lane];
}

// ---------------- logits = x@W2 + b2 ; log_softmax ----------------
__global__ __launch_bounds__(256) void k_out(const float* __restrict__ x,
    const float* __restrict__ W2, const float* __restrict__ b2,
    float* __restrict__ out, int N){
  int j = threadIdx.x & 63;
  int q = threadIdx.x >> 6;
  int n0 = blockIdx.x*32 + q*8;
  if (n0 >= N) return;
  float acc[8];
  #pragma unroll
  for (int m=0;m<8;m++) acc[m]=0.f;
  const float* xb = x + (size_t)n0*256;
  for (int k=0;k<256;k+=4){
    float w0 = W2[(k+0)*64 + j];
    float w1 = W2[(k+1)*64 + j];
    float w2 = W2[(k+2)*64 + j];
    float w3 = W2[(k+3)*64 + j];
    #pragma unroll
    for (int m=0;m<8;m++){
      float4 xv = *reinterpret_cast<const float4*>(xb + m*256 + k);
      acc[m] = fmaf(xv.x,w0,fmaf(xv.y,w1,fmaf(xv.z,w2,fmaf(xv.w,w3,acc[m]))));
    }
  }
  float bias = b2[j];
  #pragma unroll
  for (int m=0;m<8;m++){
    float l = acc[m] + bias;
    float mx = wredmax(l);
    float s  = wredsum(__expf(l-mx));
    out[(size_t)(n0+m)*64 + j] = (l-mx) - __logf(s);
  }
}

extern "C" void kernel_launch(void* const* d_in, const int* in_sizes, int n_in,
                              void* d_out, int out_size, void* d_ws, size_t ws_size,
                              hipStream_t stream){
  const float* x_in = (const float*)d_in[0];
  const int*   ei   = (const int*)d_in[1];
  const float* W1   = (const float*)d_in[2];
  const float* b1   = (const float*)d_in[3];
  const float* lin  = (const float*)d_in[4];
  const float* att  = (const float*)d_in[5];
  const float* lng  = (const float*)d_in[6];
  const float* lnb  = (const float*)d_in[7];
  const float* W2   = (const float*)d_in[8];
  const float* b2   = (const float*)d_in[9];
  float* out = (float*)d_out;

  const int N = in_sizes[0] / 256;   // 50000
  const int E = in_sizes[1] / 2;     // 800000
  const int* row = ei;
  const int* col = ei + E;

  char* basep = (char*)d_ws;
  size_t off = 0;
  auto alloc = [&](size_t bytes)->char*{
    char* p = basep + off;
    off += (bytes + 255) & ~(size_t)255;
    return p;
  };
  float*  ego    = (float*) alloc((size_t)N*256*4);
  float*  xbuf   = (float*) alloc((size_t)N*256*4);
  float*  hbuf   = (float*) alloc((size_t)N*64*4);
  float4* aws    = (float4*)alloc((size_t)E*16);
  int*    startp = (int*)   alloc((size_t)(N+1)*4);
  int*    deg    = (int*)   alloc((size_t)N*4);   // also reused as cursor
  int*    ecsr   = (int*)   alloc((size_t)E*4);
  int*    colcsr = (int*)   alloc((size_t)E*4);
  int*    bsum   = (int*)   alloc(256*4);
  int*    boff   = (int*)   alloc(256*4);

  int nbE = (E + 255)/256;   // 3125
  int nbN = (N + 255)/256;   // 196
  int nbT = (N + 63)/64;     // 782 GEMM tiles

  // CSR build
  hipMemsetAsync(deg, 0, (size_t)N*4, stream);
  k_hist<<<nbE,256,0,stream>>>(row, deg, E);
  k_scan_block<<<nbN,256,0,stream>>>(deg, startp, bsum, N);
  k_scan_bsum<<<1,256,0,stream>>>(bsum, boff, nbN);
  k_scan_add<<<nbN,256,0,stream>>>(startp, boff, N);
  hipMemsetAsync(deg, 0, (size_t)N*4, stream);     // cursor
  k_fill<<<nbE,256,0,stream>>>(row, col, startp, deg, ecsr, colcsr, E);

  // input projection + bias + relu + LN -> ego, x  (fused)
  k_gemm1_ln<<<nbT,256,0,stream>>>(x_in, W1, b1, lng, lnb, ego, xbuf, N);

  for (int L=0; L<2; ++L){
    k_hgemm<<<nbT,256,0,stream>>>(xbuf, lin + (size_t)L*256*64, hbuf, N);
    k_edge<<<(E+15)/16,256,0,stream>>>(hbuf, row, col, att + (size_t)L*64*4, aws, E);
    k_agg<<<(N+3)/4,256,0,stream>>>(hbuf, ecsr, colcsr, aws, startp, ego,
                                    lng + (size_t)(L+1)*256, lnb + (size_t)(L+1)*256,
                                    xbuf, N);
  }
  k_out<<<(N+31)/32,256,0,stream>>>(xbuf, W2, b2, out, N);
}

// Round 3
// 625.030 us; speedup vs baseline: 1.4651x; 1.1293x over previous
//
#include <hip/hip_runtime.h>
#include <cstdint>

static constexpr float kEps  = 1e-5f;
static constexpr float kBeta = 0.1f;

__device__ __forceinline__ float wredsum(float v){
  #pragma unroll
  for(int o=1;o<64;o<<=1) v += __shfl_xor(v,o);
  return v;
}
__device__ __forceinline__ float wredmax(float v){
  #pragma unroll
  for(int o=1;o<64;o<<=1) v = fmaxf(v,__shfl_xor(v,o));
  return v;
}

// ---------------- CSR build ----------------
__global__ void k_hist(const int* __restrict__ row, int* __restrict__ deg, int E){
  int e = blockIdx.x*256 + threadIdx.x;
  if (e < E) atomicAdd(&deg[row[e]], 1);
}

__global__ void k_scan_block(const int* __restrict__ deg, int* __restrict__ start,
                             int* __restrict__ bsum, int N){
  __shared__ int s[256];
  int t = threadIdx.x;
  int i = blockIdx.x*256 + t;
  int v = (i < N) ? deg[i] : 0;
  s[t] = v; __syncthreads();
  for (int off=1; off<256; off<<=1){
    int add = (t >= off) ? s[t-off] : 0;
    __syncthreads();
    s[t] += add;
    __syncthreads();
  }
  if (i < N) start[i+1] = s[t];
  if (t == 255) bsum[blockIdx.x] = s[255];
}

__global__ void k_scan_bsum(const int* __restrict__ bsum, int* __restrict__ boff, int nb){
  __shared__ int s[256];
  int t = threadIdx.x;
  int v = (t < nb) ? bsum[t] : 0;
  s[t] = v; __syncthreads();
  for (int off=1; off<256; off<<=1){
    int add = (t >= off) ? s[t-off] : 0;
    __syncthreads();
    s[t] += add;
    __syncthreads();
  }
  if (t < nb) boff[t] = s[t] - v;   // exclusive
}

__global__ void k_scan_add(int* __restrict__ start, const int* __restrict__ boff, int N){
  int i = blockIdx.x*256 + threadIdx.x;
  if (i < N) start[i+1] += boff[blockIdx.x];
  if (blockIdx.x==0 && threadIdx.x==0) start[0] = 0;
}

__global__ void k_fill(const int* __restrict__ row, const int* __restrict__ col,
                       const int* __restrict__ start, int* __restrict__ cursor,
                       int* __restrict__ ecsr, int* __restrict__ colcsr, int E){
  int e = blockIdx.x*256 + threadIdx.x;
  if (e < E){
    int r = row[e];
    int pos = atomicAdd(&cursor[r], 1);
    int i = start[r] + pos;
    ecsr[i] = e;
    colcsr[i] = col[e];
  }
}

// ---------------- GEMM1 + bias + relu + LN -> ego ----------------
// Tile 64 nodes x 256 cols, K in 8 chunks of 32. 256 threads.
// Wave w owns nodes m0=w*16..+15; lane owns cols lane*4..+3.
// xs stored transposed [k][n] -> compute reads are wave-uniform broadcasts (b128);
// ws [k][j] -> one b128 per k per lane. 5 LDS instrs per 64 FMA.
__global__ __launch_bounds__(256) void k_gemm1_ln(const float* __restrict__ x,
    const float* __restrict__ W1, const float* __restrict__ b1,
    const float* __restrict__ g, const float* __restrict__ bb,
    float* __restrict__ ego, int N){
  __shared__ float xs[32][72];    // [k][node], row stride 288B (16B aligned)
  __shared__ float ws[32][256];   // [k][col]
  const int tid  = threadIdx.x;
  const int n0   = blockIdx.x * 64;
  const int lane = tid & 63;
  const int m0   = (tid >> 6) * 16;
  const int wj   = lane * 4;
  // x-staging map: node xn, k-offsets xc..xc+7
  const int xn = tid >> 2;          // 0..63
  const int xc = (tid & 3) * 8;     // {0,8,16,24}
  // w-staging map
  const int wk = tid >> 6;          // 0..3

  float acc[16][4];
  #pragma unroll
  for (int i=0;i<16;i++)
    #pragma unroll
    for (int q=0;q<4;q++) acc[i][q]=0.f;

  for (int kc=0; kc<8; ++kc){
    int gr = min(n0 + xn, N-1);
    float4 a0 = *reinterpret_cast<const float4*>(&x[(size_t)gr*256 + kc*32 + xc]);
    float4 a1 = *reinterpret_cast<const float4*>(&x[(size_t)gr*256 + kc*32 + xc + 4]);
    xs[xc+0][xn]=a0.x; xs[xc+1][xn]=a0.y; xs[xc+2][xn]=a0.z; xs[xc+3][xn]=a0.w;
    xs[xc+4][xn]=a1.x; xs[xc+5][xn]=a1.y; xs[xc+6][xn]=a1.z; xs[xc+7][xn]=a1.w;
    #pragma unroll
    for (int s=0;s<8;s++){
      int kr = wk + s*4;
      *reinterpret_cast<float4*>(&ws[kr][wj]) =
          *reinterpret_cast<const float4*>(&W1[(size_t)(kc*32+kr)*256 + wj]);
    }
    __syncthreads();
    #pragma unroll 8
    for (int k=0;k<32;++k){
      float4 x0 = *reinterpret_cast<const float4*>(&xs[k][m0+ 0]);
      float4 x1 = *reinterpret_cast<const float4*>(&xs[k][m0+ 4]);
      float4 x2 = *reinterpret_cast<const float4*>(&xs[k][m0+ 8]);
      float4 x3 = *reinterpret_cast<const float4*>(&xs[k][m0+12]);
      float4 wv = *reinterpret_cast<const float4*>(&ws[k][wj]);
      const float xv[16] = {x0.x,x0.y,x0.z,x0.w, x1.x,x1.y,x1.z,x1.w,
                            x2.x,x2.y,x2.z,x2.w, x3.x,x3.y,x3.z,x3.w};
      #pragma unroll
      for (int i=0;i<16;i++){
        acc[i][0] = fmaf(xv[i], wv.x, acc[i][0]);
        acc[i][1] = fmaf(xv[i], wv.y, acc[i][1]);
        acc[i][2] = fmaf(xv[i], wv.z, acc[i][2]);
        acc[i][3] = fmaf(xv[i], wv.w, acc[i][3]);
      }
    }
    __syncthreads();
  }

  // epilogue: bias + relu + LN across the full wave (lane=cols)
  float4 b1v = *reinterpret_cast<const float4*>(&b1[wj]);
  float4 gv  = *reinterpret_cast<const float4*>(&g[wj]);
  float4 bbv = *reinterpret_cast<const float4*>(&bb[wj]);
  #pragma unroll
  for (int i=0;i<16;i++){
    float v0 = fmaxf(acc[i][0] + b1v.x, 0.f);
    float v1 = fmaxf(acc[i][1] + b1v.y, 0.f);
    float v2 = fmaxf(acc[i][2] + b1v.z, 0.f);
    float v3 = fmaxf(acc[i][3] + b1v.w, 0.f);
    float s  = wredsum(v0+v1+v2+v3);
    float sq = wredsum(v0*v0+v1*v1+v2*v2+v3*v3);
    int m = n0 + m0 + i;
    if (m < N){
      float mu  = s * (1.f/256.f);
      float var = sq * (1.f/256.f) - mu*mu;
      float inv = rsqrtf(fmaxf(var,0.f) + kEps);
      float4 y;
      y.x = (v0-mu)*inv*gv.x + bbv.x;
      y.y = (v1-mu)*inv*gv.y + bbv.y;
      y.z = (v2-mu)*inv*gv.z + bbv.z;
      y.w = (v3-mu)*inv*gv.w + bbv.w;
      *reinterpret_cast<float4*>(&ego[(size_t)m*256 + wj]) = y;
    }
  }
}

// ---------------- h = x @ lin_w [256->64], transposed-x tile ----------------
// Tile 64 nodes x 64 cols, K in 4 chunks of 64. Wave owns 16 nodes, lane = col.
__global__ __launch_bounds__(256) void k_hgemm(const float* __restrict__ x,
    const float* __restrict__ W, float* __restrict__ h, int N){
  __shared__ float xs[64][72];
  __shared__ float ws[64][64];
  const int tid  = threadIdx.x;
  const int n0   = blockIdx.x * 64;
  const int lane = tid & 63;
  const int m0   = (tid >> 6) * 16;
  const int xn = tid >> 2;        // 0..63
  const int xc = (tid & 3) * 16;  // {0,16,32,48}
  const int wk = tid >> 4;        // 0..15
  const int wj = (tid & 15) * 4;

  float acc[16];
  #pragma unroll
  for (int i=0;i<16;i++) acc[i]=0.f;

  for (int kc=0; kc<4; ++kc){
    int gr = min(n0 + xn, N-1);
    #pragma unroll
    for (int s=0;s<4;s++){
      float4 a = *reinterpret_cast<const float4*>(&x[(size_t)gr*256 + kc*64 + xc + s*4]);
      xs[xc+s*4+0][xn]=a.x; xs[xc+s*4+1][xn]=a.y;
      xs[xc+s*4+2][xn]=a.z; xs[xc+s*4+3][xn]=a.w;
    }
    #pragma unroll
    for (int s=0;s<4;s++){
      int kr = wk + s*16;
      *reinterpret_cast<float4*>(&ws[kr][wj]) =
          *reinterpret_cast<const float4*>(&W[(size_t)(kc*64+kr)*64 + wj]);
    }
    __syncthreads();
    #pragma unroll 8
    for (int k=0;k<64;++k){
      float4 x0 = *reinterpret_cast<const float4*>(&xs[k][m0+ 0]);
      float4 x1 = *reinterpret_cast<const float4*>(&xs[k][m0+ 4]);
      float4 x2 = *reinterpret_cast<const float4*>(&xs[k][m0+ 8]);
      float4 x3 = *reinterpret_cast<const float4*>(&xs[k][m0+12]);
      float wc = ws[k][lane];
      const float xv[16] = {x0.x,x0.y,x0.z,x0.w, x1.x,x1.y,x1.z,x1.w,
                            x2.x,x2.y,x2.z,x2.w, x3.x,x3.y,x3.z,x3.w};
      #pragma unroll
      for (int i=0;i<16;i++) acc[i] = fmaf(xv[i], wc, acc[i]);
    }
    __syncthreads();
  }
  #pragma unroll
  for (int i=0;i<16;i++){
    int m = n0 + m0 + i;
    if (m < N) h[(size_t)m*64 + lane] = acc[i];
  }
}

// ---------------- edge attention ----------------
__global__ __launch_bounds__(256) void k_edge(const float* __restrict__ h,
    const int* __restrict__ row, const int* __restrict__ col,
    const float* __restrict__ attw, float4* __restrict__ a_out, int E){
  int t = threadIdx.x;
  int g = t >> 4, l = t & 15;
  int e = blockIdx.x*16 + g;
  if (e >= E) return;
  int r = row[e], c = col[e];
  float4 hr = *reinterpret_cast<const float4*>(h + (size_t)r*64 + l*4);
  float4 hc = *reinterpret_cast<const float4*>(h + (size_t)c*64 + l*4);
  float p0 = fmaxf(0.5f*hr.x + hc.x, 0.f);
  float p1 = fmaxf(0.5f*hr.y + hc.y, 0.f);
  float p2 = fmaxf(0.5f*hr.z + hc.z, 0.f);
  float p3 = fmaxf(0.5f*hr.w + hc.w, 0.f);
  float4 t0 = *reinterpret_cast<const float4*>(attw + (l*4+0)*4);
  float4 t1 = *reinterpret_cast<const float4*>(attw + (l*4+1)*4);
  float4 t2 = *reinterpret_cast<const float4*>(attw + (l*4+2)*4);
  float4 t3 = *reinterpret_cast<const float4*>(attw + (l*4+3)*4);
  float c0 = p0*t0.x + p1*t1.x + p2*t2.x + p3*t3.x;
  float c1 = p0*t0.y + p1*t1.y + p2*t2.y + p3*t3.y;
  float c2 = p0*t0.z + p1*t1.z + p2*t2.z + p3*t3.z;
  float c3 = p0*t0.w + p1*t1.w + p2*t2.w + p3*t3.w;
  #pragma unroll
  for (int off=1; off<16; off<<=1){
    c0 += __shfl_xor(c0, off);
    c1 += __shfl_xor(c1, off);
    c2 += __shfl_xor(c2, off);
    c3 += __shfl_xor(c3, off);
  }
  if (l == 0){
    float m = fmaxf(fmaxf(c0,c1), fmaxf(c2,c3));
    float e0 = __expf(c0-m), e1 = __expf(c1-m), e2 = __expf(c2-m), e3 = __expf(c3-m);
    float invs = 1.f/(e0+e1+e2+e3);
    a_out[e] = make_float4(e0*invs, e1*invs, e2*invs, e3*invs);
  }
}

// ---------------- aggregate + relu + LN + residual blend ----------------
__global__ __launch_bounds__(256) void k_agg(const float* __restrict__ h,
    const int* __restrict__ ecsr, const int* __restrict__ colcsr,
    const float4* __restrict__ aws, const int* __restrict__ start,
    const float* __restrict__ ego, const float* __restrict__ g, const float* __restrict__ b,
    float* __restrict__ xout, int N){
  int lane = threadIdx.x & 63;
  int n = blockIdx.x*4 + (threadIdx.x >> 6);
  if (n >= N) return;
  int s0 = start[n], s1 = start[n+1];
  float a0=0.f, a1=0.f, a2=0.f, a3=0.f;
  int i = s0;
  for (; i+1 < s1; i += 2){
    int e0 = ecsr[i],   e1 = ecsr[i+1];
    int c0 = colcsr[i], c1 = colcsr[i+1];
    float4 aa0 = aws[e0], aa1 = aws[e1];
    float hv0 = h[(size_t)c0*64 + lane];
    float hv1 = h[(size_t)c1*64 + lane];
    a0 = fmaf(aa0.x, hv0, a0); a1 = fmaf(aa0.y, hv0, a1);
    a2 = fmaf(aa0.z, hv0, a2); a3 = fmaf(aa0.w, hv0, a3);
    a0 = fmaf(aa1.x, hv1, a0); a1 = fmaf(aa1.y, hv1, a1);
    a2 = fmaf(aa1.z, hv1, a2); a3 = fmaf(aa1.w, hv1, a3);
  }
  if (i < s1){
    int e = ecsr[i]; int c = colcsr[i];
    float4 aa = aws[e];
    float hv = h[(size_t)c*64 + lane];
    a0 = fmaf(aa.x, hv, a0); a1 = fmaf(aa.y, hv, a1);
    a2 = fmaf(aa.z, hv, a2); a3 = fmaf(aa.w, hv, a3);
  }
  float v0 = fmaxf(a0,0.f), v1 = fmaxf(a1,0.f), v2 = fmaxf(a2,0.f), v3 = fmaxf(a3,0.f);
  float mu = wredsum(v0+v1+v2+v3) * (1.f/256.f);
  float d0=v0-mu, d1=v1-mu, d2=v2-mu, d3=v3-mu;
  float var = wredsum(d0*d0+d1*d1+d2*d2+d3*d3) * (1.f/256.f);
  float inv = rsqrtf(var + kEps);
  size_t base = (size_t)n*256;
  float y0 = d0*inv*g[      lane] + b[      lane];
  float y1 = d1*inv*g[ 64 + lane] + b[ 64 + lane];
  float y2 = d2*inv*g[128 + lane] + b[128 + lane];
  float y3 = d3*inv*g[192 + lane] + b[192 + lane];
  xout[base +       lane] = (1.f-kBeta)*y0 + kBeta*ego[base +       lane];
  xout[base +  64 + lane] = (1.f-kBeta)*y1 + kBeta*ego[base +  64 + lane];
  xout[base + 128 + lane] = (1.f-kBeta)*y2 + kBeta*ego[base + 128 + lane];
  xout[base + 192 + lane] = (1.f-kBeta)*y3 + kBeta*ego[base + 192 + lane];
}

// ---------------- logits = x@W2 + b2 ; log_softmax (fused, tiled) ----------------
__global__ __launch_bounds__(256) void k_out(const float* __restrict__ x,
    const float* __restrict__ W2, const float* __restrict__ b2,
    float* __restrict__ out, int N){
  __shared__ float xs[64][72];
  __shared__ float ws[64][64];
  const int tid  = threadIdx.x;
  const int n0   = blockIdx.x * 64;
  const int lane = tid & 63;
  const int m0   = (tid >> 6) * 16;
  const int xn = tid >> 2;
  const int xc = (tid & 3) * 16;
  const int wk = tid >> 4;
  const int wj = (tid & 15) * 4;

  float acc[16];
  #pragma unroll
  for (int i=0;i<16;i++) acc[i]=0.f;

  for (int kc=0; kc<4; ++kc){
    int gr = min(n0 + xn, N-1);
    #pragma unroll
    for (int s=0;s<4;s++){
      float4 a = *reinterpret_cast<const float4*>(&x[(size_t)gr*256 + kc*64 + xc + s*4]);
      xs[xc+s*4+0][xn]=a.x; xs[xc+s*4+1][xn]=a.y;
      xs[xc+s*4+2][xn]=a.z; xs[xc+s*4+3][xn]=a.w;
    }
    #pragma unroll
    for (int s=0;s<4;s++){
      int kr = wk + s*16;
      *reinterpret_cast<float4*>(&ws[kr][wj]) =
          *reinterpret_cast<const float4*>(&W2[(size_t)(kc*64+kr)*64 + wj]);
    }
    __syncthreads();
    #pragma unroll 8
    for (int k=0;k<64;++k){
      float4 x0 = *reinterpret_cast<const float4*>(&xs[k][m0+ 0]);
      float4 x1 = *reinterpret_cast<const float4*>(&xs[k][m0+ 4]);
      float4 x2 = *reinterpret_cast<const float4*>(&xs[k][m0+ 8]);
      float4 x3 = *reinterpret_cast<const float4*>(&xs[k][m0+12]);
      float wc = ws[k][lane];
      const float xv[16] = {x0.x,x0.y,x0.z,x0.w, x1.x,x1.y,x1.z,x1.w,
                            x2.x,x2.y,x2.z,x2.w, x3.x,x3.y,x3.z,x3.w};
      #pragma unroll
      for (int i=0;i<16;i++) acc[i] = fmaf(xv[i], wc, acc[i]);
    }
    __syncthreads();
  }
  float bias = b2[lane];
  #pragma unroll
  for (int i=0;i<16;i++){
    float l = acc[i] + bias;
    float mx = wredmax(l);
    float sm = wredsum(__expf(l-mx));
    int m = n0 + m0 + i;
    if (m < N) out[(size_t)m*64 + lane] = (l-mx) - __logf(sm);
  }
}

extern "C" void kernel_launch(void* const* d_in, const int* in_sizes, int n_in,
                              void* d_out, int out_size, void* d_ws, size_t ws_size,
                              hipStream_t stream){
  const float* x_in = (const float*)d_in[0];
  const int*   ei   = (const int*)d_in[1];
  const float* W1   = (const float*)d_in[2];
  const float* b1   = (const float*)d_in[3];
  const float* lin  = (const float*)d_in[4];
  const float* att  = (const float*)d_in[5];
  const float* lng  = (const float*)d_in[6];
  const float* lnb  = (const float*)d_in[7];
  const float* W2   = (const float*)d_in[8];
  const float* b2   = (const float*)d_in[9];
  float* out = (float*)d_out;

  const int N = in_sizes[0] / 256;   // 50000
  const int E = in_sizes[1] / 2;     // 800000
  const int* row = ei;
  const int* col = ei + E;

  char* basep = (char*)d_ws;
  size_t off = 0;
  auto alloc = [&](size_t bytes)->char*{
    char* p = basep + off;
    off += (bytes + 255) & ~(size_t)255;
    return p;
  };
  float*  ego    = (float*) alloc((size_t)N*256*4);
  float*  xbuf   = (float*) alloc((size_t)N*256*4);
  float*  hbuf   = (float*) alloc((size_t)N*64*4);
  float4* aws    = (float4*)alloc((size_t)E*16);
  int*    startp = (int*)   alloc((size_t)(N+1)*4);
  int*    deg    = (int*)   alloc((size_t)N*4);   // also reused as cursor
  int*    ecsr   = (int*)   alloc((size_t)E*4);
  int*    colcsr = (int*)   alloc((size_t)E*4);
  int*    bsum   = (int*)   alloc(256*4);
  int*    boff   = (int*)   alloc(256*4);

  int nbE = (E + 255)/256;   // 3125
  int nbN = (N + 255)/256;   // 196
  int nbT = (N + 63)/64;     // 782 GEMM tiles

  // CSR build
  hipMemsetAsync(deg, 0, (size_t)N*4, stream);
  k_hist<<<nbE,256,0,stream>>>(row, deg, E);
  k_scan_block<<<nbN,256,0,stream>>>(deg, startp, bsum, N);
  k_scan_bsum<<<1,256,0,stream>>>(bsum, boff, nbN);
  k_scan_add<<<nbN,256,0,stream>>>(startp, boff, N);
  hipMemsetAsync(deg, 0, (size_t)N*4, stream);     // cursor
  k_fill<<<nbE,256,0,stream>>>(row, col, startp, deg, ecsr, colcsr, E);

  // input projection + bias + relu + LN -> ego only (layer 0 reads ego)
  k_gemm1_ln<<<nbT,256,0,stream>>>(x_in, W1, b1, lng, lnb, ego, N);

  for (int L=0; L<2; ++L){
    const float* xsrc = (L == 0) ? ego : xbuf;
    k_hgemm<<<nbT,256,0,stream>>>(xsrc, lin + (size_t)L*256*64, hbuf, N);
    k_edge<<<(E+15)/16,256,0,stream>>>(hbuf, row, col, att + (size_t)L*64*4, aws, E);
    k_agg<<<(N+3)/4,256,0,stream>>>(hbuf, ecsr, colcsr, aws, startp, ego,
                                    lng + (size_t)(L+1)*256, lnb + (size_t)(L+1)*256,
                                    xbuf, N);
  }
  k_out<<<nbT,256,0,stream>>>(xbuf, W2, b2, out, N);
}

// Round 4
// 620.963 us; speedup vs baseline: 1.4747x; 1.0065x over previous
//
#include <hip/hip_runtime.h>
#include <cstdint>

static constexpr float kEps  = 1e-5f;
static constexpr float kBeta = 0.1f;

__device__ __forceinline__ float wredsum(float v){
  #pragma unroll
  for(int o=1;o<64;o<<=1) v += __shfl_xor(v,o);
  return v;
}
__device__ __forceinline__ float wredmax(float v){
  #pragma unroll
  for(int o=1;o<64;o<<=1) v = fmaxf(v,__shfl_xor(v,o));
  return v;
}

// ---------------- CSR build ----------------
__global__ void k_hist(const int* __restrict__ row, int* __restrict__ deg, int E){
  int e = blockIdx.x*256 + threadIdx.x;
  if (e < E) atomicAdd(&deg[row[e]], 1);
}

__global__ void k_scan_block(const int* __restrict__ deg, int* __restrict__ start,
                             int* __restrict__ bsum, int N){
  __shared__ int s[256];
  int t = threadIdx.x;
  int i = blockIdx.x*256 + t;
  int v = (i < N) ? deg[i] : 0;
  s[t] = v; __syncthreads();
  for (int off=1; off<256; off<<=1){
    int add = (t >= off) ? s[t-off] : 0;
    __syncthreads();
    s[t] += add;
    __syncthreads();
  }
  if (i < N) start[i+1] = s[t];
  if (t == 255) bsum[blockIdx.x] = s[255];
}

__global__ void k_scan_bsum(const int* __restrict__ bsum, int* __restrict__ boff, int nb){
  __shared__ int s[256];
  int t = threadIdx.x;
  int v = (t < nb) ? bsum[t] : 0;
  s[t] = v; __syncthreads();
  for (int off=1; off<256; off<<=1){
    int add = (t >= off) ? s[t-off] : 0;
    __syncthreads();
    s[t] += add;
    __syncthreads();
  }
  if (t < nb) boff[t] = s[t] - v;   // exclusive
}

__global__ void k_scan_add(int* __restrict__ start, const int* __restrict__ boff, int N){
  int i = blockIdx.x*256 + threadIdx.x;
  if (i < N) start[i+1] += boff[blockIdx.x];
  if (blockIdx.x==0 && threadIdx.x==0) start[0] = 0;
}

__global__ void k_fill(const int* __restrict__ row, const int* __restrict__ col,
                       const int* __restrict__ start, int* __restrict__ cursor,
                       int* __restrict__ perm, int* __restrict__ colcsr, int E){
  int e = blockIdx.x*256 + threadIdx.x;
  if (e < E){
    int r = row[e];
    int pos = atomicAdd(&cursor[r], 1);
    int i = start[r] + pos;
    perm[e] = i;
    colcsr[i] = col[e];
  }
}

// ---------------- GEMM1 + bias + relu + LN -> ego ----------------
// 512 threads. Tile 128 nodes x 256 cols, K in 16 chunks of 16.
// Wave w (0..7) owns nodes m0=w*16..+15; lane owns cols lane*4..+3.
// xs transposed [k][node] (pad 132 -> 2-way store banks, free);
// compute: 4 uniform b128 broadcasts + 1 per-lane b128 per k, 64 FMA.
__global__ __launch_bounds__(512) void k_gemm1_ln(const float* __restrict__ x,
    const float* __restrict__ W1, const float* __restrict__ b1,
    const float* __restrict__ g, const float* __restrict__ bb,
    float* __restrict__ ego, int N){
  __shared__ float xs[16][132];
  __shared__ float ws[16][256];
  const int tid  = threadIdx.x;
  const int n0   = blockIdx.x * 128;
  const int lane = tid & 63;
  const int m0   = ((tid >> 6)) * 16;
  const int wj   = lane * 4;
  // x-staging: node xn (0..127), k-offset xc in {0,4,8,12}
  const int xn = tid >> 2;
  const int xc = (tid & 3) * 4;
  // w-staging: rows wk, wk+8 ; cols wj2
  const int wk  = tid >> 6;          // 0..7
  const int wj2 = (tid & 63) * 4;

  float acc[16][4];
  #pragma unroll
  for (int i=0;i<16;i++)
    #pragma unroll
    for (int q=0;q<4;q++) acc[i][q]=0.f;

  for (int kc=0; kc<16; ++kc){
    int gr = min(n0 + xn, N-1);
    float4 a = *reinterpret_cast<const float4*>(&x[(size_t)gr*256 + kc*16 + xc]);
    xs[xc+0][xn]=a.x; xs[xc+1][xn]=a.y; xs[xc+2][xn]=a.z; xs[xc+3][xn]=a.w;
    *reinterpret_cast<float4*>(&ws[wk][wj2]) =
        *reinterpret_cast<const float4*>(&W1[(size_t)(kc*16+wk)*256 + wj2]);
    *reinterpret_cast<float4*>(&ws[wk+8][wj2]) =
        *reinterpret_cast<const float4*>(&W1[(size_t)(kc*16+wk+8)*256 + wj2]);
    __syncthreads();
    #pragma unroll
    for (int k=0;k<16;++k){
      float4 x0 = *reinterpret_cast<const float4*>(&xs[k][m0+ 0]);
      float4 x1 = *reinterpret_cast<const float4*>(&xs[k][m0+ 4]);
      float4 x2 = *reinterpret_cast<const float4*>(&xs[k][m0+ 8]);
      float4 x3 = *reinterpret_cast<const float4*>(&xs[k][m0+12]);
      float4 wv = *reinterpret_cast<const float4*>(&ws[k][wj]);
      const float xv[16] = {x0.x,x0.y,x0.z,x0.w, x1.x,x1.y,x1.z,x1.w,
                            x2.x,x2.y,x2.z,x2.w, x3.x,x3.y,x3.z,x3.w};
      #pragma unroll
      for (int i=0;i<16;i++){
        acc[i][0] = fmaf(xv[i], wv.x, acc[i][0]);
        acc[i][1] = fmaf(xv[i], wv.y, acc[i][1]);
        acc[i][2] = fmaf(xv[i], wv.z, acc[i][2]);
        acc[i][3] = fmaf(xv[i], wv.w, acc[i][3]);
      }
    }
    __syncthreads();
  }

  // epilogue: bias + relu + LN across the full wave (lane=cols)
  float4 b1v = *reinterpret_cast<const float4*>(&b1[wj]);
  float4 gv  = *reinterpret_cast<const float4*>(&g[wj]);
  float4 bbv = *reinterpret_cast<const float4*>(&bb[wj]);
  #pragma unroll
  for (int i=0;i<16;i++){
    float v0 = fmaxf(acc[i][0] + b1v.x, 0.f);
    float v1 = fmaxf(acc[i][1] + b1v.y, 0.f);
    float v2 = fmaxf(acc[i][2] + b1v.z, 0.f);
    float v3 = fmaxf(acc[i][3] + b1v.w, 0.f);
    float s  = wredsum(v0+v1+v2+v3);
    float sq = wredsum(v0*v0+v1*v1+v2*v2+v3*v3);
    int m = n0 + m0 + i;
    if (m < N){
      float mu  = s * (1.f/256.f);
      float var = sq * (1.f/256.f) - mu*mu;
      float inv = rsqrtf(fmaxf(var,0.f) + kEps);
      float4 y;
      y.x = (v0-mu)*inv*gv.x + bbv.x;
      y.y = (v1-mu)*inv*gv.y + bbv.y;
      y.z = (v2-mu)*inv*gv.z + bbv.z;
      y.w = (v3-mu)*inv*gv.w + bbv.w;
      *reinterpret_cast<float4*>(&ego[(size_t)m*256 + wj]) = y;
    }
  }
}

// ---------------- h = x @ lin_w [256->64], transposed-x tile ----------------
__global__ __launch_bounds__(256) void k_hgemm(const float* __restrict__ x,
    const float* __restrict__ W, float* __restrict__ h, int N){
  __shared__ float xs[64][72];
  __shared__ float ws[64][64];
  const int tid  = threadIdx.x;
  const int n0   = blockIdx.x * 64;
  const int lane = tid & 63;
  const int m0   = (tid >> 6) * 16;
  const int xn = tid >> 2;        // 0..63
  const int xc = (tid & 3) * 16;  // {0,16,32,48}
  const int wk = tid >> 4;        // 0..15
  const int wj = (tid & 15) * 4;

  float acc[16];
  #pragma unroll
  for (int i=0;i<16;i++) acc[i]=0.f;

  for (int kc=0; kc<4; ++kc){
    int gr = min(n0 + xn, N-1);
    #pragma unroll
    for (int s=0;s<4;s++){
      float4 a = *reinterpret_cast<const float4*>(&x[(size_t)gr*256 + kc*64 + xc + s*4]);
      xs[xc+s*4+0][xn]=a.x; xs[xc+s*4+1][xn]=a.y;
      xs[xc+s*4+2][xn]=a.z; xs[xc+s*4+3][xn]=a.w;
    }
    #pragma unroll
    for (int s=0;s<4;s++){
      int kr = wk + s*16;
      *reinterpret_cast<float4*>(&ws[kr][wj]) =
          *reinterpret_cast<const float4*>(&W[(size_t)(kc*64+kr)*64 + wj]);
    }
    __syncthreads();
    #pragma unroll 8
    for (int k=0;k<64;++k){
      float4 x0 = *reinterpret_cast<const float4*>(&xs[k][m0+ 0]);
      float4 x1 = *reinterpret_cast<const float4*>(&xs[k][m0+ 4]);
      float4 x2 = *reinterpret_cast<const float4*>(&xs[k][m0+ 8]);
      float4 x3 = *reinterpret_cast<const float4*>(&xs[k][m0+12]);
      float wc = ws[k][lane];
      const float xv[16] = {x0.x,x0.y,x0.z,x0.w, x1.x,x1.y,x1.z,x1.w,
                            x2.x,x2.y,x2.z,x2.w, x3.x,x3.y,x3.z,x3.w};
      #pragma unroll
      for (int i=0;i<16;i++) acc[i] = fmaf(xv[i], wc, acc[i]);
    }
    __syncthreads();
  }
  #pragma unroll
  for (int i=0;i<16;i++){
    int m = n0 + m0 + i;
    if (m < N) h[(size_t)m*64 + lane] = acc[i];
  }
}

// ---------------- edge attention -> a_csr[perm[e]] ----------------
// grid-strided; 16 lanes per edge; attw hoisted to registers.
__global__ __launch_bounds__(256) void k_edge(const float* __restrict__ h,
    const int* __restrict__ row, const int* __restrict__ col,
    const int* __restrict__ perm,
    const float* __restrict__ attw, float4* __restrict__ a_csr, int E){
  const int l = threadIdx.x & 15;
  float4 t0 = *reinterpret_cast<const float4*>(attw + (l*4+0)*4);
  float4 t1 = *reinterpret_cast<const float4*>(attw + (l*4+1)*4);
  float4 t2 = *reinterpret_cast<const float4*>(attw + (l*4+2)*4);
  float4 t3 = *reinterpret_cast<const float4*>(attw + (l*4+3)*4);
  const int g0     = blockIdx.x*16 + (threadIdx.x >> 4);
  const int stride = gridDim.x*16;
  for (int e = g0; e < E; e += stride){
    int r = row[e], c = col[e];
    float4 hr = *reinterpret_cast<const float4*>(h + (size_t)r*64 + l*4);
    float4 hc = *reinterpret_cast<const float4*>(h + (size_t)c*64 + l*4);
    float p0 = fmaxf(0.5f*hr.x + hc.x, 0.f);
    float p1 = fmaxf(0.5f*hr.y + hc.y, 0.f);
    float p2 = fmaxf(0.5f*hr.z + hc.z, 0.f);
    float p3 = fmaxf(0.5f*hr.w + hc.w, 0.f);
    float c0 = p0*t0.x + p1*t1.x + p2*t2.x + p3*t3.x;
    float c1 = p0*t0.y + p1*t1.y + p2*t2.y + p3*t3.y;
    float c2 = p0*t0.z + p1*t1.z + p2*t2.z + p3*t3.z;
    float c3 = p0*t0.w + p1*t1.w + p2*t2.w + p3*t3.w;
    #pragma unroll
    for (int off=1; off<16; off<<=1){
      c0 += __shfl_xor(c0, off);
      c1 += __shfl_xor(c1, off);
      c2 += __shfl_xor(c2, off);
      c3 += __shfl_xor(c3, off);
    }
    if (l == 0){
      float m = fmaxf(fmaxf(c0,c1), fmaxf(c2,c3));
      float e0 = __expf(c0-m), e1 = __expf(c1-m), e2 = __expf(c2-m), e3 = __expf(c3-m);
      float invs = 1.f/(e0+e1+e2+e3);
      a_csr[perm[e]] = make_float4(e0*invs, e1*invs, e2*invs, e3*invs);
    }
  }
}

// ---------------- aggregate + relu + LN + residual blend ----------------
// a_csr/colcsr are sequential streams now; only h is a random gather.
__global__ __launch_bounds__(256) void k_agg(const float* __restrict__ h,
    const int* __restrict__ colcsr,
    const float4* __restrict__ a_csr, const int* __restrict__ start,
    const float* __restrict__ ego, const float* __restrict__ g, const float* __restrict__ b,
    float* __restrict__ xout, int N){
  int lane = threadIdx.x & 63;
  int n = blockIdx.x*4 + (threadIdx.x >> 6);
  if (n >= N) return;
  int s0 = start[n], s1 = start[n+1];
  float a0=0.f, a1=0.f, a2=0.f, a3=0.f;
  int i = s0;
  for (; i+1 < s1; i += 2){
    int c0 = colcsr[i], c1 = colcsr[i+1];
    float4 aa0 = a_csr[i], aa1 = a_csr[i+1];
    float hv0 = h[(size_t)c0*64 + lane];
    float hv1 = h[(size_t)c1*64 + lane];
    a0 = fmaf(aa0.x, hv0, a0); a1 = fmaf(aa0.y, hv0, a1);
    a2 = fmaf(aa0.z, hv0, a2); a3 = fmaf(aa0.w, hv0, a3);
    a0 = fmaf(aa1.x, hv1, a0); a1 = fmaf(aa1.y, hv1, a1);
    a2 = fmaf(aa1.z, hv1, a2); a3 = fmaf(aa1.w, hv1, a3);
  }
  if (i < s1){
    int c = colcsr[i];
    float4 aa = a_csr[i];
    float hv = h[(size_t)c*64 + lane];
    a0 = fmaf(aa.x, hv, a0); a1 = fmaf(aa.y, hv, a1);
    a2 = fmaf(aa.z, hv, a2); a3 = fmaf(aa.w, hv, a3);
  }
  float v0 = fmaxf(a0,0.f), v1 = fmaxf(a1,0.f), v2 = fmaxf(a2,0.f), v3 = fmaxf(a3,0.f);
  float mu = wredsum(v0+v1+v2+v3) * (1.f/256.f);
  float d0=v0-mu, d1=v1-mu, d2=v2-mu, d3=v3-mu;
  float var = wredsum(d0*d0+d1*d1+d2*d2+d3*d3) * (1.f/256.f);
  float inv = rsqrtf(var + kEps);
  size_t base = (size_t)n*256;
  float y0 = d0*inv*g[      lane] + b[      lane];
  float y1 = d1*inv*g[ 64 + lane] + b[ 64 + lane];
  float y2 = d2*inv*g[128 + lane] + b[128 + lane];
  float y3 = d3*inv*g[192 + lane] + b[192 + lane];
  xout[base +       lane] = (1.f-kBeta)*y0 + kBeta*ego[base +       lane];
  xout[base +  64 + lane] = (1.f-kBeta)*y1 + kBeta*ego[base +  64 + lane];
  xout[base + 128 + lane] = (1.f-kBeta)*y2 + kBeta*ego[base + 128 + lane];
  xout[base + 192 + lane] = (1.f-kBeta)*y3 + kBeta*ego[base + 192 + lane];
}

// ---------------- logits = x@W2 + b2 ; log_softmax (fused, tiled) ----------------
__global__ __launch_bounds__(256) void k_out(const float* __restrict__ x,
    const float* __restrict__ W2, const float* __restrict__ b2,
    float* __restrict__ out, int N){
  __shared__ float xs[64][72];
  __shared__ float ws[64][64];
  const int tid  = threadIdx.x;
  const int n0   = blockIdx.x * 64;
  const int lane = tid & 63;
  const int m0   = (tid >> 6) * 16;
  const int xn = tid >> 2;
  const int xc = (tid & 3) * 16;
  const int wk = tid >> 4;
  const int wj = (tid & 15) * 4;

  float acc[16];
  #pragma unroll
  for (int i=0;i<16;i++) acc[i]=0.f;

  for (int kc=0; kc<4; ++kc){
    int gr = min(n0 + xn, N-1);
    #pragma unroll
    for (int s=0;s<4;s++){
      float4 a = *reinterpret_cast<const float4*>(&x[(size_t)gr*256 + kc*64 + xc + s*4]);
      xs[xc+s*4+0][xn]=a.x; xs[xc+s*4+1][xn]=a.y;
      xs[xc+s*4+2][xn]=a.z; xs[xc+s*4+3][xn]=a.w;
    }
    #pragma unroll
    for (int s=0;s<4;s++){
      int kr = wk + s*16;
      *reinterpret_cast<float4*>(&ws[kr][wj]) =
          *reinterpret_cast<const float4*>(&W2[(size_t)(kc*64+kr)*64 + wj]);
    }
    __syncthreads();
    #pragma unroll 8
    for (int k=0;k<64;++k){
      float4 x0 = *reinterpret_cast<const float4*>(&xs[k][m0+ 0]);
      float4 x1 = *reinterpret_cast<const float4*>(&xs[k][m0+ 4]);
      float4 x2 = *reinterpret_cast<const float4*>(&xs[k][m0+ 8]);
      float4 x3 = *reinterpret_cast<const float4*>(&xs[k][m0+12]);
      float wc = ws[k][lane];
      const float xv[16] = {x0.x,x0.y,x0.z,x0.w, x1.x,x1.y,x1.z,x1.w,
                            x2.x,x2.y,x2.z,x2.w, x3.x,x3.y,x3.z,x3.w};
      #pragma unroll
      for (int i=0;i<16;i++) acc[i] = fmaf(xv[i], wc, acc[i]);
    }
    __syncthreads();
  }
  float bias = b2[lane];
  #pragma unroll
  for (int i=0;i<16;i++){
    float l = acc[i] + bias;
    float mx = wredmax(l);
    float sm = wredsum(__expf(l-mx));
    int m = n0 + m0 + i;
    if (m < N) out[(size_t)m*64 + lane] = (l-mx) - __logf(sm);
  }
}

extern "C" void kernel_launch(void* const* d_in, const int* in_sizes, int n_in,
                              void* d_out, int out_size, void* d_ws, size_t ws_size,
                              hipStream_t stream){
  const float* x_in = (const float*)d_in[0];
  const int*   ei   = (const int*)d_in[1];
  const float* W1   = (const float*)d_in[2];
  const float* b1   = (const float*)d_in[3];
  const float* lin  = (const float*)d_in[4];
  const float* att  = (const float*)d_in[5];
  const float* lng  = (const float*)d_in[6];
  const float* lnb  = (const float*)d_in[7];
  const float* W2   = (const float*)d_in[8];
  const float* b2   = (const float*)d_in[9];
  float* out = (float*)d_out;

  const int N = in_sizes[0] / 256;   // 50000
  const int E = in_sizes[1] / 2;     // 800000
  const int* row = ei;
  const int* col = ei + E;

  char* basep = (char*)d_ws;
  size_t off = 0;
  auto alloc = [&](size_t bytes)->char*{
    char* p = basep + off;
    off += (bytes + 255) & ~(size_t)255;
    return p;
  };
  float*  ego    = (float*) alloc((size_t)N*256*4);
  float*  xbuf   = (float*) alloc((size_t)N*256*4);
  float*  hbuf   = (float*) alloc((size_t)N*64*4);
  float4* acsr   = (float4*)alloc((size_t)E*16);
  int*    startp = (int*)   alloc((size_t)(N+1)*4);
  int*    deg    = (int*)   alloc((size_t)N*4);   // also reused as cursor
  int*    perm   = (int*)   alloc((size_t)E*4);
  int*    colcsr = (int*)   alloc((size_t)E*4);
  int*    bsum   = (int*)   alloc(256*4);
  int*    boff   = (int*)   alloc(256*4);

  int nbE = (E + 255)/256;   // 3125
  int nbN = (N + 255)/256;   // 196
  int nbT = (N + 63)/64;     // 782 tiles (64-node kernels)
  int nbG = (N + 127)/128;   // 391 tiles (gemm1)

  // CSR build
  hipMemsetAsync(deg, 0, (size_t)N*4, stream);
  k_hist<<<nbE,256,0,stream>>>(row, deg, E);
  k_scan_block<<<nbN,256,0,stream>>>(deg, startp, bsum, N);
  k_scan_bsum<<<1,256,0,stream>>>(bsum, boff, nbN);
  k_scan_add<<<nbN,256,0,stream>>>(startp, boff, N);
  hipMemsetAsync(deg, 0, (size_t)N*4, stream);     // cursor
  k_fill<<<nbE,256,0,stream>>>(row, col, startp, deg, perm, colcsr, E);

  // input projection + bias + relu + LN -> ego only (layer 0 reads ego)
  k_gemm1_ln<<<nbG,512,0,stream>>>(x_in, W1, b1, lng, lnb, ego, N);

  for (int L=0; L<2; ++L){
    const float* xsrc = (L == 0) ? ego : xbuf;
    k_hgemm<<<nbT,256,0,stream>>>(xsrc, lin + (size_t)L*256*64, hbuf, N);
    k_edge<<<1024,256,0,stream>>>(hbuf, row, col, perm, att + (size_t)L*64*4, acsr, E);
    k_agg<<<(N+3)/4,256,0,stream>>>(hbuf, colcsr, acsr, startp, ego,
                                    lng + (size_t)(L+1)*256, lnb + (size_t)(L+1)*256,
                                    xbuf, N);
  }
  k_out<<<nbT,256,0,stream>>>(xbuf, W2, b2, out, N);
}

// Round 5
// 542.528 us; speedup vs baseline: 1.6879x; 1.1446x over previous
//
#include <hip/hip_runtime.h>
#include <cstdint>

static constexpr float kEps  = 1e-5f;
static constexpr float kBeta = 0.1f;

typedef __attribute__((ext_vector_type(8))) short bf16x8;
typedef __attribute__((ext_vector_type(4))) float f32x4;

__device__ __forceinline__ float wredsum(float v){
  #pragma unroll
  for(int o=1;o<64;o<<=1) v += __shfl_xor(v,o);
  return v;
}
__device__ __forceinline__ float wredmax(float v){
  #pragma unroll
  for(int o=1;o<64;o<<=1) v = fmaxf(v,__shfl_xor(v,o));
  return v;
}

__device__ __forceinline__ ushort f2bf(float f){
  uint u = __float_as_uint(f);
  u += 0x7fff + ((u>>16)&1);      // round-to-nearest-even
  return (ushort)(u>>16);
}
__device__ __forceinline__ float bf2f(ushort h){
  return __uint_as_float(((uint)h)<<16);
}

// ---------------- CSR build ----------------
__global__ void k_hist(const int* __restrict__ row, int* __restrict__ deg, int E){
  int e = blockIdx.x*256 + threadIdx.x;
  if (e < E) atomicAdd(&deg[row[e]], 1);
}

__global__ void k_scan_block(const int* __restrict__ deg, int* __restrict__ start,
                             int* __restrict__ bsum, int N){
  __shared__ int s[256];
  int t = threadIdx.x;
  int i = blockIdx.x*256 + t;
  int v = (i < N) ? deg[i] : 0;
  s[t] = v; __syncthreads();
  for (int off=1; off<256; off<<=1){
    int add = (t >= off) ? s[t-off] : 0;
    __syncthreads();
    s[t] += add;
    __syncthreads();
  }
  if (i < N) start[i+1] = s[t];
  if (t == 255) bsum[blockIdx.x] = s[255];
}

__global__ void k_scan_bsum(const int* __restrict__ bsum, int* __restrict__ boff, int nb){
  __shared__ int s[256];
  int t = threadIdx.x;
  int v = (t < nb) ? bsum[t] : 0;
  s[t] = v; __syncthreads();
  for (int off=1; off<256; off<<=1){
    int add = (t >= off) ? s[t-off] : 0;
    __syncthreads();
    s[t] += add;
    __syncthreads();
  }
  if (t < nb) boff[t] = s[t] - v;   // exclusive
}

__global__ void k_scan_add(int* __restrict__ start, const int* __restrict__ boff, int N){
  int i = blockIdx.x*256 + threadIdx.x;
  if (i < N) start[i+1] += boff[blockIdx.x];
  if (blockIdx.x==0 && threadIdx.x==0) start[0] = 0;
}

__global__ void k_fill(const int* __restrict__ row, const int* __restrict__ col,
                       const int* __restrict__ start, int* __restrict__ cursor,
                       int* __restrict__ perm, int* __restrict__ colcsr, int E){
  int e = blockIdx.x*256 + threadIdx.x;
  if (e < E){
    int r = row[e];
    int pos = atomicAdd(&cursor[r], 1);
    int i = start[r] + pos;
    perm[e] = i;
    colcsr[i] = col[e];
  }
}

// ---------------- W1 -> bf16, k-chunk-contiguous layout ----------------
// W1s[kc][col][kk] with k = kc*32+kk : addr = kc*8192 + col*32 + kk
__global__ void k_prep_w1(const float* __restrict__ W1, ushort* __restrict__ W1s){
  int i = blockIdx.x*256 + threadIdx.x;   // i = k*256 + col
  int k = i >> 8, col = i & 255;
  W1s[(k>>5)*8192 + col*32 + (k&31)] = f2bf(W1[i]);
}

// ---------------- GEMM1 (MFMA, split-x bf16) + bias + relu + LN -> ego ----
// 256 threads = 4 waves. Tile 64 rows x 256 cols, BK=32 (8 chunks).
// Wave w owns cols [w*64, w*64+64) x all 64 rows -> 16 C-tiles of 16x16.
// A = x (split hi/lo bf16), B = W1 bf16. acc fp32.
// mfma_f32_16x16x32_bf16: A lane: row=l&15, k=(l>>4)*8+j ; B lane: col=l&15,
// same k ; D lane: col=l&15, row=(l>>4)*4+reg  [m89-verified].
__global__ __launch_bounds__(256) void k_gemm1_mfma(const float* __restrict__ x,
    const ushort* __restrict__ W1s, const float* __restrict__ b1,
    const float* __restrict__ g, const float* __restrict__ bb,
    float* __restrict__ ego, int N){
  __shared__ ushort xh[64][40];
  __shared__ ushort xl[64][40];
  __shared__ ushort wl[256][40];
  __shared__ float psum[64][4], psq[64][4];
  __shared__ float mub[64], ivb[64];

  const int tid = threadIdx.x;
  const int n0  = blockIdx.x*64;
  const int w   = tid>>6;
  const int l   = tid&63;
  const int l15 = l&15;
  const int lg  = l>>4;            // 0..3
  const int cb  = w*64;            // wave col base
  // staging maps
  const int sxr = tid>>2;          // x row 0..63
  const int sxk = (tid&3)*8;       // k offset {0,8,16,24}

  f32x4 acc[4][4];
  #pragma unroll
  for (int rt=0;rt<4;rt++)
    #pragma unroll
    for (int ct=0;ct<4;ct++)
      acc[rt][ct] = (f32x4){0.f,0.f,0.f,0.f};

  for (int kc=0; kc<8; ++kc){
    if (kc) __syncthreads();
    // stage x: 8 fp32 -> hi/lo bf16
    const float* xp = &x[(size_t)min(n0+sxr, N-1)*256 + kc*32 + sxk];
    float4 v0 = *reinterpret_cast<const float4*>(xp);
    float4 v1 = *reinterpret_cast<const float4*>(xp+4);
    const float vv[8] = {v0.x,v0.y,v0.z,v0.w,v1.x,v1.y,v1.z,v1.w};
    bf16x8 hv, lv;
    #pragma unroll
    for (int j=0;j<8;j++){
      ushort hb = f2bf(vv[j]);
      hv[j] = (short)hb;
      lv[j] = (short)f2bf(vv[j] - bf2f(hb));
    }
    *reinterpret_cast<bf16x8*>(&xh[sxr][sxk]) = hv;
    *reinterpret_cast<bf16x8*>(&xl[sxr][sxk]) = lv;
    // stage W chunk: col = tid, 32 k (fully coalesced 16KB)
    const ushort* wp = &W1s[kc*8192 + tid*32];
    #pragma unroll
    for (int s=0;s<4;s++)
      *reinterpret_cast<bf16x8*>(&wl[tid][s*8]) =
          *reinterpret_cast<const bf16x8*>(wp + s*8);
    __syncthreads();
    // compute: 8 A-reads + 4 B-reads, 32 MFMA
    bf16x8 ah[4], al[4];
    #pragma unroll
    for (int rt=0;rt<4;rt++){
      ah[rt] = *reinterpret_cast<const bf16x8*>(&xh[rt*16+l15][lg*8]);
      al[rt] = *reinterpret_cast<const bf16x8*>(&xl[rt*16+l15][lg*8]);
    }
    #pragma unroll
    for (int ct=0;ct<4;ct++){
      bf16x8 bv = *reinterpret_cast<const bf16x8*>(&wl[cb+ct*16+l15][lg*8]);
      #pragma unroll
      for (int rt=0;rt<4;rt++){
        acc[rt][ct] = __builtin_amdgcn_mfma_f32_16x16x32_bf16(al[rt], bv, acc[rt][ct], 0,0,0);
        acc[rt][ct] = __builtin_amdgcn_mfma_f32_16x16x32_bf16(ah[rt], bv, acc[rt][ct], 0,0,0);
      }
    }
  }

  // epilogue: bias + relu (in place), LN via cross-wave LDS reduction
  float b1v[4], gv[4], bbv[4];
  #pragma unroll
  for (int ct=0;ct<4;ct++){
    int col = cb + ct*16 + l15;
    b1v[ct] = b1[col]; gv[ct] = g[col]; bbv[ct] = bb[col];
  }
  #pragma unroll
  for (int rt=0;rt<4;rt++)
    #pragma unroll
    for (int ct=0;ct<4;ct++)
      #pragma unroll
      for (int r=0;r<4;r++)
        acc[rt][ct][r] = fmaxf(acc[rt][ct][r] + b1v[ct], 0.f);

  #pragma unroll
  for (int rt=0;rt<4;rt++){
    #pragma unroll
    for (int r=0;r<4;r++){
      float s = acc[rt][0][r]+acc[rt][1][r]+acc[rt][2][r]+acc[rt][3][r];
      float q = acc[rt][0][r]*acc[rt][0][r]+acc[rt][1][r]*acc[rt][1][r]
              + acc[rt][2][r]*acc[rt][2][r]+acc[rt][3][r]*acc[rt][3][r];
      #pragma unroll
      for (int o=1;o<16;o<<=1){ s += __shfl_xor(s,o); q += __shfl_xor(q,o); }
      if (l15 == 0){
        int row = rt*16 + lg*4 + r;
        psum[row][w] = s; psq[row][w] = q;
      }
    }
  }
  __syncthreads();
  if (tid < 64){
    float s = psum[tid][0]+psum[tid][1]+psum[tid][2]+psum[tid][3];
    float q = psq[tid][0]+psq[tid][1]+psq[tid][2]+psq[tid][3];
    float mu  = s * (1.f/256.f);
    float var = q * (1.f/256.f) - mu*mu;
    mub[tid] = mu;
    ivb[tid] = rsqrtf(fmaxf(var, 0.f) + kEps);
  }
  __syncthreads();
  #pragma unroll
  for (int rt=0;rt<4;rt++){
    #pragma unroll
    for (int r=0;r<4;r++){
      int row  = rt*16 + lg*4 + r;
      int grow = n0 + row;
      if (grow < N){
        float mu = mub[row], inv = ivb[row];
        size_t base = (size_t)grow*256 + cb + l15;
        #pragma unroll
        for (int ct=0;ct<4;ct++)
          ego[base + ct*16] = (acc[rt][ct][r]-mu)*inv*gv[ct] + bbv[ct];
      }
    }
  }
}

// ---------------- h = x @ lin_w [256->64], transposed-x tile ----------------
__global__ __launch_bounds__(256) void k_hgemm(const float* __restrict__ x,
    const float* __restrict__ W, float* __restrict__ h, int N){
  __shared__ float xs[64][72];
  __shared__ float ws[64][64];
  const int tid  = threadIdx.x;
  const int n0   = blockIdx.x * 64;
  const int lane = tid & 63;
  const int m0   = (tid >> 6) * 16;
  const int xn = tid >> 2;        // 0..63
  const int xc = (tid & 3) * 16;  // {0,16,32,48}
  const int wk = tid >> 4;        // 0..15
  const int wj = (tid & 15) * 4;

  float acc[16];
  #pragma unroll
  for (int i=0;i<16;i++) acc[i]=0.f;

  for (int kc=0; kc<4; ++kc){
    int gr = min(n0 + xn, N-1);
    #pragma unroll
    for (int s=0;s<4;s++){
      float4 a = *reinterpret_cast<const float4*>(&x[(size_t)gr*256 + kc*64 + xc + s*4]);
      xs[xc+s*4+0][xn]=a.x; xs[xc+s*4+1][xn]=a.y;
      xs[xc+s*4+2][xn]=a.z; xs[xc+s*4+3][xn]=a.w;
    }
    #pragma unroll
    for (int s=0;s<4;s++){
      int kr = wk + s*16;
      *reinterpret_cast<float4*>(&ws[kr][wj]) =
          *reinterpret_cast<const float4*>(&W[(size_t)(kc*64+kr)*64 + wj]);
    }
    __syncthreads();
    #pragma unroll 8
    for (int k=0;k<64;++k){
      float4 x0 = *reinterpret_cast<const float4*>(&xs[k][m0+ 0]);
      float4 x1 = *reinterpret_cast<const float4*>(&xs[k][m0+ 4]);
      float4 x2 = *reinterpret_cast<const float4*>(&xs[k][m0+ 8]);
      float4 x3 = *reinterpret_cast<const float4*>(&xs[k][m0+12]);
      float wc = ws[k][lane];
      const float xv[16] = {x0.x,x0.y,x0.z,x0.w, x1.x,x1.y,x1.z,x1.w,
                            x2.x,x2.y,x2.z,x2.w, x3.x,x3.y,x3.z,x3.w};
      #pragma unroll
      for (int i=0;i<16;i++) acc[i] = fmaf(xv[i], wc, acc[i]);
    }
    __syncthreads();
  }
  #pragma unroll
  for (int i=0;i<16;i++){
    int m = n0 + m0 + i;
    if (m < N) h[(size_t)m*64 + lane] = acc[i];
  }
}

// ---------------- edge attention -> a_csr[perm[e]] ----------------
__global__ __launch_bounds__(256) void k_edge(const float* __restrict__ h,
    const int* __restrict__ row, const int* __restrict__ col,
    const int* __restrict__ perm,
    const float* __restrict__ attw, float4* __restrict__ a_csr, int E){
  const int l = threadIdx.x & 15;
  float4 t0 = *reinterpret_cast<const float4*>(attw + (l*4+0)*4);
  float4 t1 = *reinterpret_cast<const float4*>(attw + (l*4+1)*4);
  float4 t2 = *reinterpret_cast<const float4*>(attw + (l*4+2)*4);
  float4 t3 = *reinterpret_cast<const float4*>(attw + (l*4+3)*4);
  const int g0     = blockIdx.x*16 + (threadIdx.x >> 4);
  const int stride = gridDim.x*16;
  for (int e = g0; e < E; e += stride){
    int r = row[e], c = col[e];
    float4 hr = *reinterpret_cast<const float4*>(h + (size_t)r*64 + l*4);
    float4 hc = *reinterpret_cast<const float4*>(h + (size_t)c*64 + l*4);
    float p0 = fmaxf(0.5f*hr.x + hc.x, 0.f);
    float p1 = fmaxf(0.5f*hr.y + hc.y, 0.f);
    float p2 = fmaxf(0.5f*hr.z + hc.z, 0.f);
    float p3 = fmaxf(0.5f*hr.w + hc.w, 0.f);
    float c0 = p0*t0.x + p1*t1.x + p2*t2.x + p3*t3.x;
    float c1 = p0*t0.y + p1*t1.y + p2*t2.y + p3*t3.y;
    float c2 = p0*t0.z + p1*t1.z + p2*t2.z + p3*t3.z;
    float c3 = p0*t0.w + p1*t1.w + p2*t2.w + p3*t3.w;
    #pragma unroll
    for (int off=1; off<16; off<<=1){
      c0 += __shfl_xor(c0, off);
      c1 += __shfl_xor(c1, off);
      c2 += __shfl_xor(c2, off);
      c3 += __shfl_xor(c3, off);
    }
    if (l == 0){
      float m = fmaxf(fmaxf(c0,c1), fmaxf(c2,c3));
      float e0 = __expf(c0-m), e1 = __expf(c1-m), e2 = __expf(c2-m), e3 = __expf(c3-m);
      float invs = 1.f/(e0+e1+e2+e3);
      a_csr[perm[e]] = make_float4(e0*invs, e1*invs, e2*invs, e3*invs);
    }
  }
}

// ---------------- aggregate + relu + LN + residual blend ----------------
__global__ __launch_bounds__(256) void k_agg(const float* __restrict__ h,
    const int* __restrict__ colcsr,
    const float4* __restrict__ a_csr, const int* __restrict__ start,
    const float* __restrict__ ego, const float* __restrict__ g, const float* __restrict__ b,
    float* __restrict__ xout, int N){
  int lane = threadIdx.x & 63;
  int n = blockIdx.x*4 + (threadIdx.x >> 6);
  if (n >= N) return;
  int s0 = start[n], s1 = start[n+1];
  float a0=0.f, a1=0.f, a2=0.f, a3=0.f;
  int i = s0;
  for (; i+1 < s1; i += 2){
    int c0 = colcsr[i], c1 = colcsr[i+1];
    float4 aa0 = a_csr[i], aa1 = a_csr[i+1];
    float hv0 = h[(size_t)c0*64 + lane];
    float hv1 = h[(size_t)c1*64 + lane];
    a0 = fmaf(aa0.x, hv0, a0); a1 = fmaf(aa0.y, hv0, a1);
    a2 = fmaf(aa0.z, hv0, a2); a3 = fmaf(aa0.w, hv0, a3);
    a0 = fmaf(aa1.x, hv1, a0); a1 = fmaf(aa1.y, hv1, a1);
    a2 = fmaf(aa1.z, hv1, a2); a3 = fmaf(aa1.w, hv1, a3);
  }
  if (i < s1){
    int c = colcsr[i];
    float4 aa = a_csr[i];
    float hv = h[(size_t)c*64 + lane];
    a0 = fmaf(aa.x, hv, a0); a1 = fmaf(aa.y, hv, a1);
    a2 = fmaf(aa.z, hv, a2); a3 = fmaf(aa.w, hv, a3);
  }
  float v0 = fmaxf(a0,0.f), v1 = fmaxf(a1,0.f), v2 = fmaxf(a2,0.f), v3 = fmaxf(a3,0.f);
  float mu = wredsum(v0+v1+v2+v3) * (1.f/256.f);
  float d0=v0-mu, d1=v1-mu, d2=v2-mu, d3=v3-mu;
  float var = wredsum(d0*d0+d1*d1+d2*d2+d3*d3) * (1.f/256.f);
  float inv = rsqrtf(var + kEps);
  size_t base = (size_t)n*256;
  float y0 = d0*inv*g[      lane] + b[      lane];
  float y1 = d1*inv*g[ 64 + lane] + b[ 64 + lane];
  float y2 = d2*inv*g[128 + lane] + b[128 + lane];
  float y3 = d3*inv*g[192 + lane] + b[192 + lane];
  xout[base +       lane] = (1.f-kBeta)*y0 + kBeta*ego[base +       lane];
  xout[base +  64 + lane] = (1.f-kBeta)*y1 + kBeta*ego[base +  64 + lane];
  xout[base + 128 + lane] = (1.f-kBeta)*y2 + kBeta*ego[base + 128 + lane];
  xout[base + 192 + lane] = (1.f-kBeta)*y3 + kBeta*ego[base + 192 + lane];
}

// ---------------- logits = x@W2 + b2 ; log_softmax (fused, tiled) ----------------
__global__ __launch_bounds__(256) void k_out(const float* __restrict__ x,
    const float* __restrict__ W2, const float* __restrict__ b2,
    float* __restrict__ out, int N){
  __shared__ float xs[64][72];
  __shared__ float ws[64][64];
  const int tid  = threadIdx.x;
  const int n0   = blockIdx.x * 64;
  const int lane = tid & 63;
  const int m0   = (tid >> 6) * 16;
  const int xn = tid >> 2;
  const int xc = (tid & 3) * 16;
  const int wk = tid >> 4;
  const int wj = (tid & 15) * 4;

  float acc[16];
  #pragma unroll
  for (int i=0;i<16;i++) acc[i]=0.f;

  for (int kc=0; kc<4; ++kc){
    int gr = min(n0 + xn, N-1);
    #pragma unroll
    for (int s=0;s<4;s++){
      float4 a = *reinterpret_cast<const float4*>(&x[(size_t)gr*256 + kc*64 + xc + s*4]);
      xs[xc+s*4+0][xn]=a.x; xs[xc+s*4+1][xn]=a.y;
      xs[xc+s*4+2][xn]=a.z; xs[xc+s*4+3][xn]=a.w;
    }
    #pragma unroll
    for (int s=0;s<4;s++){
      int kr = wk + s*16;
      *reinterpret_cast<float4*>(&ws[kr][wj]) =
          *reinterpret_cast<const float4*>(&W2[(size_t)(kc*64+kr)*64 + wj]);
    }
    __syncthreads();
    #pragma unroll 8
    for (int k=0;k<64;++k){
      float4 x0 = *reinterpret_cast<const float4*>(&xs[k][m0+ 0]);
      float4 x1 = *reinterpret_cast<const float4*>(&xs[k][m0+ 4]);
      float4 x2 = *reinterpret_cast<const float4*>(&xs[k][m0+ 8]);
      float4 x3 = *reinterpret_cast<const float4*>(&xs[k][m0+12]);
      float wc = ws[k][lane];
      const float xv[16] = {x0.x,x0.y,x0.z,x0.w, x1.x,x1.y,x1.z,x1.w,
                            x2.x,x2.y,x2.z,x2.w, x3.x,x3.y,x3.z,x3.w};
      #pragma unroll
      for (int i=0;i<16;i++) acc[i] = fmaf(xv[i], wc, acc[i]);
    }
    __syncthreads();
  }
  float bias = b2[lane];
  #pragma unroll
  for (int i=0;i<16;i++){
    float l = acc[i] + bias;
    float mx = wredmax(l);
    float sm = wredsum(__expf(l-mx));
    int m = n0 + m0 + i;
    if (m < N) out[(size_t)m*64 + lane] = (l-mx) - __logf(sm);
  }
}

extern "C" void kernel_launch(void* const* d_in, const int* in_sizes, int n_in,
                              void* d_out, int out_size, void* d_ws, size_t ws_size,
                              hipStream_t stream){
  const float* x_in = (const float*)d_in[0];
  const int*   ei   = (const int*)d_in[1];
  const float* W1   = (const float*)d_in[2];
  const float* b1   = (const float*)d_in[3];
  const float* lin  = (const float*)d_in[4];
  const float* att  = (const float*)d_in[5];
  const float* lng  = (const float*)d_in[6];
  const float* lnb  = (const float*)d_in[7];
  const float* W2   = (const float*)d_in[8];
  const float* b2   = (const float*)d_in[9];
  float* out = (float*)d_out;

  const int N = in_sizes[0] / 256;   // 50000
  const int E = in_sizes[1] / 2;     // 800000
  const int* row = ei;
  const int* col = ei + E;

  char* basep = (char*)d_ws;
  size_t off = 0;
  auto alloc = [&](size_t bytes)->char*{
    char* p = basep + off;
    off += (bytes + 255) & ~(size_t)255;
    return p;
  };
  float*  ego    = (float*) alloc((size_t)N*256*4);
  float*  xbuf   = (float*) alloc((size_t)N*256*4);
  float*  hbuf   = (float*) alloc((size_t)N*64*4);
  float4* acsr   = (float4*)alloc((size_t)E*16);
  int*    startp = (int*)   alloc((size_t)(N+1)*4);
  int*    deg    = (int*)   alloc((size_t)N*4);   // also reused as cursor
  int*    perm   = (int*)   alloc((size_t)E*4);
  int*    colcsr = (int*)   alloc((size_t)E*4);
  int*    bsum   = (int*)   alloc(256*4);
  int*    boff   = (int*)   alloc(256*4);
  ushort* W1s    = (ushort*)alloc((size_t)256*256*2);

  int nbE = (E + 255)/256;   // 3125
  int nbN = (N + 255)/256;   // 196
  int nbT = (N + 63)/64;     // 782 tiles

  // CSR build
  hipMemsetAsync(deg, 0, (size_t)N*4, stream);
  k_hist<<<nbE,256,0,stream>>>(row, deg, E);
  k_scan_block<<<nbN,256,0,stream>>>(deg, startp, bsum, N);
  k_scan_bsum<<<1,256,0,stream>>>(bsum, boff, nbN);
  k_scan_add<<<nbN,256,0,stream>>>(startp, boff, N);
  hipMemsetAsync(deg, 0, (size_t)N*4, stream);     // cursor
  k_fill<<<nbE,256,0,stream>>>(row, col, startp, deg, perm, colcsr, E);

  // W1 -> bf16 packed; then MFMA projection + bias + relu + LN -> ego
  k_prep_w1<<<256,256,0,stream>>>(W1, W1s);
  k_gemm1_mfma<<<nbT,256,0,stream>>>(x_in, W1s, b1, lng, lnb, ego, N);

  for (int L=0; L<2; ++L){
    const float* xsrc = (L == 0) ? ego : xbuf;
    k_hgemm<<<nbT,256,0,stream>>>(xsrc, lin + (size_t)L*256*64, hbuf, N);
    k_edge<<<1024,256,0,stream>>>(hbuf, row, col, perm, att + (size_t)L*64*4, acsr, E);
    k_agg<<<(N+3)/4,256,0,stream>>>(hbuf, colcsr, acsr, startp, ego,
                                    lng + (size_t)(L+1)*256, lnb + (size_t)(L+1)*256,
                                    xbuf, N);
  }
  k_out<<<nbT,256,0,stream>>>(xbuf, W2, b2, out, N);
}

// Round 6
// 434.936 us; speedup vs baseline: 2.1054x; 1.2474x over previous
//
#include <hip/hip_runtime.h>
#include <cstdint>

static constexpr float kEps  = 1e-5f;
static constexpr float kBeta = 0.1f;

typedef __attribute__((ext_vector_type(8))) short bf16x8;
typedef __attribute__((ext_vector_type(4))) float f32x4;

__device__ __forceinline__ float wredsum(float v){
  #pragma unroll
  for(int o=1;o<64;o<<=1) v += __shfl_xor(v,o);
  return v;
}
__device__ __forceinline__ float wredmax(float v){
  #pragma unroll
  for(int o=1;o<64;o<<=1) v = fmaxf(v,__shfl_xor(v,o));
  return v;
}

__device__ __forceinline__ ushort f2bf(float f){
  uint u = __float_as_uint(f);
  u += 0x7fff + ((u>>16)&1);      // round-to-nearest-even
  return (ushort)(u>>16);
}
__device__ __forceinline__ float bf2f(ushort h){
  return __uint_as_float(((uint)h)<<16);
}

// ---------------- CSR build ----------------
__global__ void k_hist(const int* __restrict__ row, int* __restrict__ deg, int E){
  int e = blockIdx.x*256 + threadIdx.x;
  if (e < E) atomicAdd(&deg[row[e]], 1);
}

__global__ void k_scan_block(const int* __restrict__ deg, int* __restrict__ start,
                             int* __restrict__ bsum, int N){
  __shared__ int s[256];
  int t = threadIdx.x;
  int i = blockIdx.x*256 + t;
  int v = (i < N) ? deg[i] : 0;
  s[t] = v; __syncthreads();
  for (int off=1; off<256; off<<=1){
    int add = (t >= off) ? s[t-off] : 0;
    __syncthreads();
    s[t] += add;
    __syncthreads();
  }
  if (i < N) start[i+1] = s[t];
  if (t == 255) bsum[blockIdx.x] = s[255];
}

__global__ void k_scan_bsum(const int* __restrict__ bsum, int* __restrict__ boff, int nb){
  __shared__ int s[256];
  int t = threadIdx.x;
  int v = (t < nb) ? bsum[t] : 0;
  s[t] = v; __syncthreads();
  for (int off=1; off<256; off<<=1){
    int add = (t >= off) ? s[t-off] : 0;
    __syncthreads();
    s[t] += add;
    __syncthreads();
  }
  if (t < nb) boff[t] = s[t] - v;   // exclusive
}

__global__ void k_scan_add(int* __restrict__ start, const int* __restrict__ boff, int N){
  int i = blockIdx.x*256 + threadIdx.x;
  if (i < N) start[i+1] += boff[blockIdx.x];
  if (blockIdx.x==0 && threadIdx.x==0) start[0] = 0;
}

__global__ void k_fill(const int* __restrict__ row, const int* __restrict__ col,
                       const int* __restrict__ start, int* __restrict__ cursor,
                       int* __restrict__ colcsr, int E){
  int e = blockIdx.x*256 + threadIdx.x;
  if (e < E){
    int r = row[e];
    int pos = atomicAdd(&cursor[r], 1);
    colcsr[start[r] + pos] = col[e];
  }
}

// ---------------- W1 -> bf16, k-chunk-contiguous layout ----------------
__global__ void k_prep_w1(const float* __restrict__ W1, ushort* __restrict__ W1s){
  int i = blockIdx.x*256 + threadIdx.x;   // i = k*256 + col
  int k = i >> 8, col = i & 255;
  W1s[(k>>5)*8192 + col*32 + (k&31)] = f2bf(W1[i]);
}

// ---------------- GEMM1 (MFMA, split-x bf16) + bias + relu + LN -> ego ----
__global__ __launch_bounds__(256) void k_gemm1_mfma(const float* __restrict__ x,
    const ushort* __restrict__ W1s, const float* __restrict__ b1,
    const float* __restrict__ g, const float* __restrict__ bb,
    float* __restrict__ ego, int N){
  __shared__ ushort xh[64][40];
  __shared__ ushort xl[64][40];
  __shared__ ushort wl[256][40];
  __shared__ float psum[64][4], psq[64][4];
  __shared__ float mub[64], ivb[64];

  const int tid = threadIdx.x;
  const int n0  = blockIdx.x*64;
  const int w   = tid>>6;
  const int l   = tid&63;
  const int l15 = l&15;
  const int lg  = l>>4;            // 0..3
  const int cb  = w*64;            // wave col base
  const int sxr = tid>>2;          // x row 0..63
  const int sxk = (tid&3)*8;       // k offset {0,8,16,24}

  f32x4 acc[4][4];
  #pragma unroll
  for (int rt=0;rt<4;rt++)
    #pragma unroll
    for (int ct=0;ct<4;ct++)
      acc[rt][ct] = (f32x4){0.f,0.f,0.f,0.f};

  for (int kc=0; kc<8; ++kc){
    if (kc) __syncthreads();
    const float* xp = &x[(size_t)min(n0+sxr, N-1)*256 + kc*32 + sxk];
    float4 v0 = *reinterpret_cast<const float4*>(xp);
    float4 v1 = *reinterpret_cast<const float4*>(xp+4);
    const float vv[8] = {v0.x,v0.y,v0.z,v0.w,v1.x,v1.y,v1.z,v1.w};
    bf16x8 hv, lv;
    #pragma unroll
    for (int j=0;j<8;j++){
      ushort hb = f2bf(vv[j]);
      hv[j] = (short)hb;
      lv[j] = (short)f2bf(vv[j] - bf2f(hb));
    }
    *reinterpret_cast<bf16x8*>(&xh[sxr][sxk]) = hv;
    *reinterpret_cast<bf16x8*>(&xl[sxr][sxk]) = lv;
    const ushort* wp = &W1s[kc*8192 + tid*32];
    #pragma unroll
    for (int s=0;s<4;s++)
      *reinterpret_cast<bf16x8*>(&wl[tid][s*8]) =
          *reinterpret_cast<const bf16x8*>(wp + s*8);
    __syncthreads();
    bf16x8 ah[4], al[4];
    #pragma unroll
    for (int rt=0;rt<4;rt++){
      ah[rt] = *reinterpret_cast<const bf16x8*>(&xh[rt*16+l15][lg*8]);
      al[rt] = *reinterpret_cast<const bf16x8*>(&xl[rt*16+l15][lg*8]);
    }
    #pragma unroll
    for (int ct=0;ct<4;ct++){
      bf16x8 bv = *reinterpret_cast<const bf16x8*>(&wl[cb+ct*16+l15][lg*8]);
      #pragma unroll
      for (int rt=0;rt<4;rt++){
        acc[rt][ct] = __builtin_amdgcn_mfma_f32_16x16x32_bf16(al[rt], bv, acc[rt][ct], 0,0,0);
        acc[rt][ct] = __builtin_amdgcn_mfma_f32_16x16x32_bf16(ah[rt], bv, acc[rt][ct], 0,0,0);
      }
    }
  }

  float b1v[4], gv[4], bbv[4];
  #pragma unroll
  for (int ct=0;ct<4;ct++){
    int col = cb + ct*16 + l15;
    b1v[ct] = b1[col]; gv[ct] = g[col]; bbv[ct] = bb[col];
  }
  #pragma unroll
  for (int rt=0;rt<4;rt++)
    #pragma unroll
    for (int ct=0;ct<4;ct++)
      #pragma unroll
      for (int r=0;r<4;r++)
        acc[rt][ct][r] = fmaxf(acc[rt][ct][r] + b1v[ct], 0.f);

  #pragma unroll
  for (int rt=0;rt<4;rt++){
    #pragma unroll
    for (int r=0;r<4;r++){
      float s = acc[rt][0][r]+acc[rt][1][r]+acc[rt][2][r]+acc[rt][3][r];
      float q = acc[rt][0][r]*acc[rt][0][r]+acc[rt][1][r]*acc[rt][1][r]
              + acc[rt][2][r]*acc[rt][2][r]+acc[rt][3][r]*acc[rt][3][r];
      #pragma unroll
      for (int o=1;o<16;o<<=1){ s += __shfl_xor(s,o); q += __shfl_xor(q,o); }
      if (l15 == 0){
        int row = rt*16 + lg*4 + r;
        psum[row][w] = s; psq[row][w] = q;
      }
    }
  }
  __syncthreads();
  if (tid < 64){
    float s = psum[tid][0]+psum[tid][1]+psum[tid][2]+psum[tid][3];
    float q = psq[tid][0]+psq[tid][1]+psq[tid][2]+psq[tid][3];
    float mu  = s * (1.f/256.f);
    float var = q * (1.f/256.f) - mu*mu;
    mub[tid] = mu;
    ivb[tid] = rsqrtf(fmaxf(var, 0.f) + kEps);
  }
  __syncthreads();
  #pragma unroll
  for (int rt=0;rt<4;rt++){
    #pragma unroll
    for (int r=0;r<4;r++){
      int row  = rt*16 + lg*4 + r;
      int grow = n0 + row;
      if (grow < N){
        float mu = mub[row], inv = ivb[row];
        size_t base = (size_t)grow*256 + cb + l15;
        #pragma unroll
        for (int ct=0;ct<4;ct++)
          ego[base + ct*16] = (acc[rt][ct][r]-mu)*inv*gv[ct] + bbv[ct];
      }
    }
  }
}

// ---------------- h = x @ lin_w [256->64] -> bf16 ----------------
__global__ __launch_bounds__(256) void k_hgemm(const float* __restrict__ x,
    const float* __restrict__ W, ushort* __restrict__ h, int N){
  __shared__ float xs[64][72];
  __shared__ float ws[64][64];
  const int tid  = threadIdx.x;
  const int n0   = blockIdx.x * 64;
  const int lane = tid & 63;
  const int m0   = (tid >> 6) * 16;
  const int xn = tid >> 2;        // 0..63
  const int xc = (tid & 3) * 16;  // {0,16,32,48}
  const int wk = tid >> 4;        // 0..15
  const int wj = (tid & 15) * 4;

  float acc[16];
  #pragma unroll
  for (int i=0;i<16;i++) acc[i]=0.f;

  for (int kc=0; kc<4; ++kc){
    int gr = min(n0 + xn, N-1);
    #pragma unroll
    for (int s=0;s<4;s++){
      float4 a = *reinterpret_cast<const float4*>(&x[(size_t)gr*256 + kc*64 + xc + s*4]);
      xs[xc+s*4+0][xn]=a.x; xs[xc+s*4+1][xn]=a.y;
      xs[xc+s*4+2][xn]=a.z; xs[xc+s*4+3][xn]=a.w;
    }
    #pragma unroll
    for (int s=0;s<4;s++){
      int kr = wk + s*16;
      *reinterpret_cast<float4*>(&ws[kr][wj]) =
          *reinterpret_cast<const float4*>(&W[(size_t)(kc*64+kr)*64 + wj]);
    }
    __syncthreads();
    #pragma unroll 8
    for (int k=0;k<64;++k){
      float4 x0 = *reinterpret_cast<const float4*>(&xs[k][m0+ 0]);
      float4 x1 = *reinterpret_cast<const float4*>(&xs[k][m0+ 4]);
      float4 x2 = *reinterpret_cast<const float4*>(&xs[k][m0+ 8]);
      float4 x3 = *reinterpret_cast<const float4*>(&xs[k][m0+12]);
      float wc = ws[k][lane];
      const float xv[16] = {x0.x,x0.y,x0.z,x0.w, x1.x,x1.y,x1.z,x1.w,
                            x2.x,x2.y,x2.z,x2.w, x3.x,x3.y,x3.z,x3.w};
      #pragma unroll
      for (int i=0;i<16;i++) acc[i] = fmaf(xv[i], wc, acc[i]);
    }
    __syncthreads();
  }
  #pragma unroll
  for (int i=0;i<16;i++){
    int m = n0 + m0 + i;
    if (m < N) h[(size_t)m*64 + lane] = f2bf(acc[i]);
  }
}

// ------- fused edge attention + aggregate + relu + LN + residual -------
// One wave per node; 4 groups x 16 lanes; group walks every 4th CSR edge.
// Lane owns dims d = l15*4..+3. Per edge: 8B bf16 gather, inline softmax
// via 16-lane butterfly, 16-FMA accumulate. Group g writes gate g.
__global__ __launch_bounds__(256) void k_att_agg(
    const ushort* __restrict__ h,      // [N][64] bf16
    const int* __restrict__ colcsr, const int* __restrict__ start,
    const float* __restrict__ attw,    // [64][4]
    const float* __restrict__ ego,
    const float* __restrict__ g, const float* __restrict__ b,
    float* __restrict__ xout, int N){
  const int lane = threadIdx.x & 63;
  const int grp  = lane >> 4;
  const int l15  = lane & 15;
  const int n = blockIdx.x*4 + (threadIdx.x >> 6);
  if (n >= N) return;

  float4 aw[4];
  #pragma unroll
  for (int j=0;j<4;j++)
    aw[j] = *reinterpret_cast<const float4*>(&attw[(l15*4+j)*4]);

  float hr2[4];
  {
    ushort4 hv = *reinterpret_cast<const ushort4*>(&h[(size_t)n*64 + l15*4]);
    hr2[0]=0.5f*bf2f(hv.x); hr2[1]=0.5f*bf2f(hv.y);
    hr2[2]=0.5f*bf2f(hv.z); hr2[3]=0.5f*bf2f(hv.w);
  }

  float acc[4][4];   // [gate][dim j]
  #pragma unroll
  for (int c=0;c<4;c++)
    #pragma unroll
    for (int j=0;j<4;j++) acc[c][j]=0.f;

  const int s0 = start[n], s1 = start[n+1];
  for (int i = s0 + grp; i < s1; i += 4){
    int cn = colcsr[i];
    ushort4 hv = *reinterpret_cast<const ushort4*>(&h[(size_t)cn*64 + l15*4]);
    float hc0=bf2f(hv.x), hc1=bf2f(hv.y), hc2=bf2f(hv.z), hc3=bf2f(hv.w);
    float p0 = fmaxf(hr2[0]+hc0, 0.f);
    float p1 = fmaxf(hr2[1]+hc1, 0.f);
    float p2 = fmaxf(hr2[2]+hc2, 0.f);
    float p3 = fmaxf(hr2[3]+hc3, 0.f);
    float q0 = p0*aw[0].x + p1*aw[1].x + p2*aw[2].x + p3*aw[3].x;
    float q1 = p0*aw[0].y + p1*aw[1].y + p2*aw[2].y + p3*aw[3].y;
    float q2 = p0*aw[0].z + p1*aw[1].z + p2*aw[2].z + p3*aw[3].z;
    float q3 = p0*aw[0].w + p1*aw[1].w + p2*aw[2].w + p3*aw[3].w;
    #pragma unroll
    for (int o=1;o<16;o<<=1){
      q0 += __shfl_xor(q0,o);
      q1 += __shfl_xor(q1,o);
      q2 += __shfl_xor(q2,o);
      q3 += __shfl_xor(q3,o);
    }
    float m = fmaxf(fmaxf(q0,q1), fmaxf(q2,q3));
    float e0=__expf(q0-m), e1=__expf(q1-m), e2=__expf(q2-m), e3=__expf(q3-m);
    float inv = 1.f/(e0+e1+e2+e3);
    float a0=e0*inv, a1=e1*inv, a2=e2*inv, a3=e3*inv;
    acc[0][0]=fmaf(a0,hc0,acc[0][0]); acc[0][1]=fmaf(a0,hc1,acc[0][1]);
    acc[0][2]=fmaf(a0,hc2,acc[0][2]); acc[0][3]=fmaf(a0,hc3,acc[0][3]);
    acc[1][0]=fmaf(a1,hc0,acc[1][0]); acc[1][1]=fmaf(a1,hc1,acc[1][1]);
    acc[1][2]=fmaf(a1,hc2,acc[1][2]); acc[1][3]=fmaf(a1,hc3,acc[1][3]);
    acc[2][0]=fmaf(a2,hc0,acc[2][0]); acc[2][1]=fmaf(a2,hc1,acc[2][1]);
    acc[2][2]=fmaf(a2,hc2,acc[2][2]); acc[2][3]=fmaf(a2,hc3,acc[2][3]);
    acc[3][0]=fmaf(a3,hc0,acc[3][0]); acc[3][1]=fmaf(a3,hc1,acc[3][1]);
    acc[3][2]=fmaf(a3,hc2,acc[3][2]); acc[3][3]=fmaf(a3,hc3,acc[3][3]);
  }

  // combine the 4 groups (offsets 16,32); then all lanes hold totals
  #pragma unroll
  for (int c=0;c<4;c++)
    #pragma unroll
    for (int j=0;j<4;j++){
      float v = acc[c][j];
      v += __shfl_xor(v,16);
      v += __shfl_xor(v,32);
      acc[c][j] = fmaxf(v, 0.f);   // relu
    }

  // LN stats over 256 cols: per-lane partial of 16 vals, reduce over l15
  float s=0.f, sq=0.f;
  #pragma unroll
  for (int c=0;c<4;c++)
    #pragma unroll
    for (int j=0;j<4;j++){ float v=acc[c][j]; s+=v; sq+=v*v; }
  #pragma unroll
  for (int o=1;o<16;o<<=1){ s += __shfl_xor(s,o); sq += __shfl_xor(sq,o); }
  float mu  = s * (1.f/256.f);
  float var = sq * (1.f/256.f) - mu*mu;
  float inv = rsqrtf(fmaxf(var,0.f) + kEps);

  // group g writes gate g: cols grp*64 + l15*4 .. +3
  int colb = grp*64 + l15*4;
  float4 gv  = *reinterpret_cast<const float4*>(&g[colb]);
  float4 bv  = *reinterpret_cast<const float4*>(&b[colb]);
  size_t base = (size_t)n*256 + colb;
  float4 ev  = *reinterpret_cast<const float4*>(&ego[base]);
  float4 y;
  y.x = (1.f-kBeta)*((acc[grp][0]-mu)*inv*gv.x + bv.x) + kBeta*ev.x;
  y.y = (1.f-kBeta)*((acc[grp][1]-mu)*inv*gv.y + bv.y) + kBeta*ev.y;
  y.z = (1.f-kBeta)*((acc[grp][2]-mu)*inv*gv.z + bv.z) + kBeta*ev.z;
  y.w = (1.f-kBeta)*((acc[grp][3]-mu)*inv*gv.w + bv.w) + kBeta*ev.w;
  *reinterpret_cast<float4*>(&xout[base]) = y;
}

// ---------------- logits = x@W2 + b2 ; log_softmax (fused, tiled) ----------------
__global__ __launch_bounds__(256) void k_out(const float* __restrict__ x,
    const float* __restrict__ W2, const float* __restrict__ b2,
    float* __restrict__ out, int N){
  __shared__ float xs[64][72];
  __shared__ float ws[64][64];
  const int tid  = threadIdx.x;
  const int n0   = blockIdx.x * 64;
  const int lane = tid & 63;
  const int m0   = (tid >> 6) * 16;
  const int xn = tid >> 2;
  const int xc = (tid & 3) * 16;
  const int wk = tid >> 4;
  const int wj = (tid & 15) * 4;

  float acc[16];
  #pragma unroll
  for (int i=0;i<16;i++) acc[i]=0.f;

  for (int kc=0; kc<4; ++kc){
    int gr = min(n0 + xn, N-1);
    #pragma unroll
    for (int s=0;s<4;s++){
      float4 a = *reinterpret_cast<const float4*>(&x[(size_t)gr*256 + kc*64 + xc + s*4]);
      xs[xc+s*4+0][xn]=a.x; xs[xc+s*4+1][xn]=a.y;
      xs[xc+s*4+2][xn]=a.z; xs[xc+s*4+3][xn]=a.w;
    }
    #pragma unroll
    for (int s=0;s<4;s++){
      int kr = wk + s*16;
      *reinterpret_cast<float4*>(&ws[kr][wj]) =
          *reinterpret_cast<const float4*>(&W2[(size_t)(kc*64+kr)*64 + wj]);
    }
    __syncthreads();
    #pragma unroll 8
    for (int k=0;k<64;++k){
      float4 x0 = *reinterpret_cast<const float4*>(&xs[k][m0+ 0]);
      float4 x1 = *reinterpret_cast<const float4*>(&xs[k][m0+ 4]);
      float4 x2 = *reinterpret_cast<const float4*>(&xs[k][m0+ 8]);
      float4 x3 = *reinterpret_cast<const float4*>(&xs[k][m0+12]);
      float wc = ws[k][lane];
      const float xv[16] = {x0.x,x0.y,x0.z,x0.w, x1.x,x1.y,x1.z,x1.w,
                            x2.x,x2.y,x2.z,x2.w, x3.x,x3.y,x3.z,x3.w};
      #pragma unroll
      for (int i=0;i<16;i++) acc[i] = fmaf(xv[i], wc, acc[i]);
    }
    __syncthreads();
  }
  float bias = b2[lane];
  #pragma unroll
  for (int i=0;i<16;i++){
    float l = acc[i] + bias;
    float mx = wredmax(l);
    float sm = wredsum(__expf(l-mx));
    int m = n0 + m0 + i;
    if (m < N) out[(size_t)m*64 + lane] = (l-mx) - __logf(sm);
  }
}

extern "C" void kernel_launch(void* const* d_in, const int* in_sizes, int n_in,
                              void* d_out, int out_size, void* d_ws, size_t ws_size,
                              hipStream_t stream){
  const float* x_in = (const float*)d_in[0];
  const int*   ei   = (const int*)d_in[1];
  const float* W1   = (const float*)d_in[2];
  const float* b1   = (const float*)d_in[3];
  const float* lin  = (const float*)d_in[4];
  const float* att  = (const float*)d_in[5];
  const float* lng  = (const float*)d_in[6];
  const float* lnb  = (const float*)d_in[7];
  const float* W2   = (const float*)d_in[8];
  const float* b2   = (const float*)d_in[9];
  float* out = (float*)d_out;

  const int N = in_sizes[0] / 256;   // 50000
  const int E = in_sizes[1] / 2;     // 800000
  const int* row = ei;
  const int* col = ei + E;

  char* basep = (char*)d_ws;
  size_t off = 0;
  auto alloc = [&](size_t bytes)->char*{
    char* p = basep + off;
    off += (bytes + 255) & ~(size_t)255;
    return p;
  };
  float*  ego    = (float*) alloc((size_t)N*256*4);
  float*  xbuf   = (float*) alloc((size_t)N*256*4);
  ushort* hbuf   = (ushort*)alloc((size_t)N*64*2);
  int*    startp = (int*)   alloc((size_t)(N+1)*4);
  int*    deg    = (int*)   alloc((size_t)N*4);   // also reused as cursor
  int*    colcsr = (int*)   alloc((size_t)E*4);
  int*    bsum   = (int*)   alloc(256*4);
  int*    boff   = (int*)   alloc(256*4);
  ushort* W1s    = (ushort*)alloc((size_t)256*256*2);

  int nbE = (E + 255)/256;   // 3125
  int nbN = (N + 255)/256;   // 196
  int nbT = (N + 63)/64;     // 782 tiles

  // CSR build
  hipMemsetAsync(deg, 0, (size_t)N*4, stream);
  k_hist<<<nbE,256,0,stream>>>(row, deg, E);
  k_scan_block<<<nbN,256,0,stream>>>(deg, startp, bsum, N);
  k_scan_bsum<<<1,256,0,stream>>>(bsum, boff, nbN);
  k_scan_add<<<nbN,256,0,stream>>>(startp, boff, N);
  hipMemsetAsync(deg, 0, (size_t)N*4, stream);     // cursor
  k_fill<<<nbE,256,0,stream>>>(row, col, startp, deg, colcsr, E);

  // W1 -> bf16 packed; MFMA projection + bias + relu + LN -> ego
  k_prep_w1<<<256,256,0,stream>>>(W1, W1s);
  k_gemm1_mfma<<<nbT,256,0,stream>>>(x_in, W1s, b1, lng, lnb, ego, N);

  for (int L=0; L<2; ++L){
    const float* xsrc = (L == 0) ? ego : xbuf;
    k_hgemm<<<nbT,256,0,stream>>>(xsrc, lin + (size_t)L*256*64, hbuf, N);
    k_att_agg<<<(N+3)/4,256,0,stream>>>(hbuf, colcsr, startp,
                                        att + (size_t)L*64*4, ego,
                                        lng + (size_t)(L+1)*256, lnb + (size_t)(L+1)*256,
                                        xbuf, N);
  }
  k_out<<<nbT,256,0,stream>>>(xbuf, W2, b2, out, N);
}

// Round 7
// 417.410 us; speedup vs baseline: 2.1938x; 1.0420x over previous
//
#include <hip/hip_runtime.h>
#include <cstdint>

static constexpr float kEps  = 1e-5f;
static constexpr float kBeta = 0.1f;

typedef __attribute__((ext_vector_type(8))) short bf16x8;
typedef __attribute__((ext_vector_type(4))) float f32x4;

__device__ __forceinline__ float wredsum(float v){
  #pragma unroll
  for(int o=1;o<64;o<<=1) v += __shfl_xor(v,o);
  return v;
}
__device__ __forceinline__ float wredmax(float v){
  #pragma unroll
  for(int o=1;o<64;o<<=1) v = fmaxf(v,__shfl_xor(v,o));
  return v;
}

__device__ __forceinline__ ushort f2bf(float f){
  uint u = __float_as_uint(f);
  u += 0x7fff + ((u>>16)&1);      // round-to-nearest-even
  return (ushort)(u>>16);
}
__device__ __forceinline__ float bf2f(ushort h){
  return __uint_as_float(((uint)h)<<16);
}

// ---------------- CSR build ----------------
__global__ void k_hist(const int* __restrict__ row, int* __restrict__ deg, int E){
  int e = blockIdx.x*256 + threadIdx.x;
  if (e < E) atomicAdd(&deg[row[e]], 1);
}

__global__ void k_scan_block(const int* __restrict__ deg, int* __restrict__ start,
                             int* __restrict__ bsum, int N){
  __shared__ int s[256];
  int t = threadIdx.x;
  int i = blockIdx.x*256 + t;
  int v = (i < N) ? deg[i] : 0;
  s[t] = v; __syncthreads();
  for (int off=1; off<256; off<<=1){
    int add = (t >= off) ? s[t-off] : 0;
    __syncthreads();
    s[t] += add;
    __syncthreads();
  }
  if (i < N) start[i+1] = s[t];
  if (t == 255) bsum[blockIdx.x] = s[255];
}

__global__ void k_scan_bsum(const int* __restrict__ bsum, int* __restrict__ boff, int nb){
  __shared__ int s[256];
  int t = threadIdx.x;
  int v = (t < nb) ? bsum[t] : 0;
  s[t] = v; __syncthreads();
  for (int off=1; off<256; off<<=1){
    int add = (t >= off) ? s[t-off] : 0;
    __syncthreads();
    s[t] += add;
    __syncthreads();
  }
  if (t < nb) boff[t] = s[t] - v;   // exclusive
}

__global__ void k_scan_add(int* __restrict__ start, const int* __restrict__ boff, int N){
  int i = blockIdx.x*256 + threadIdx.x;
  if (i < N) start[i+1] += boff[blockIdx.x];
  if (blockIdx.x==0 && threadIdx.x==0) start[0] = 0;
}

__global__ void k_fill(const int* __restrict__ row, const int* __restrict__ col,
                       const int* __restrict__ start, int* __restrict__ cursor,
                       int* __restrict__ rowcsr, int* __restrict__ colcsr, int E){
  int e = blockIdx.x*256 + threadIdx.x;
  if (e < E){
    int r = row[e];
    int pos = atomicAdd(&cursor[r], 1);
    int i = start[r] + pos;
    rowcsr[i] = r;
    colcsr[i] = col[e];
  }
}

// ---------------- W1 -> bf16, k-chunk-contiguous layout ----------------
__global__ void k_prep_w1(const float* __restrict__ W1, ushort* __restrict__ W1s){
  int i = blockIdx.x*256 + threadIdx.x;   // i = k*256 + col
  int k = i >> 8, col = i & 255;
  W1s[(k>>5)*8192 + col*32 + (k&31)] = f2bf(W1[i]);
}

// ---------------- GEMM1 (MFMA, split-x bf16) + bias + relu + LN -> ego ----
__global__ __launch_bounds__(256) void k_gemm1_mfma(const float* __restrict__ x,
    const ushort* __restrict__ W1s, const float* __restrict__ b1,
    const float* __restrict__ g, const float* __restrict__ bb,
    float* __restrict__ ego, int N){
  __shared__ ushort xh[64][40];
  __shared__ ushort xl[64][40];
  __shared__ ushort wl[256][40];
  __shared__ float psum[64][4], psq[64][4];
  __shared__ float mub[64], ivb[64];

  const int tid = threadIdx.x;
  const int n0  = blockIdx.x*64;
  const int w   = tid>>6;
  const int l   = tid&63;
  const int l15 = l&15;
  const int lg  = l>>4;            // 0..3
  const int cb  = w*64;            // wave col base
  const int sxr = tid>>2;          // x row 0..63
  const int sxk = (tid&3)*8;       // k offset {0,8,16,24}

  f32x4 acc[4][4];
  #pragma unroll
  for (int rt=0;rt<4;rt++)
    #pragma unroll
    for (int ct=0;ct<4;ct++)
      acc[rt][ct] = (f32x4){0.f,0.f,0.f,0.f};

  for (int kc=0; kc<8; ++kc){
    if (kc) __syncthreads();
    const float* xp = &x[(size_t)min(n0+sxr, N-1)*256 + kc*32 + sxk];
    float4 v0 = *reinterpret_cast<const float4*>(xp);
    float4 v1 = *reinterpret_cast<const float4*>(xp+4);
    const float vv[8] = {v0.x,v0.y,v0.z,v0.w,v1.x,v1.y,v1.z,v1.w};
    bf16x8 hv, lv;
    #pragma unroll
    for (int j=0;j<8;j++){
      ushort hb = f2bf(vv[j]);
      hv[j] = (short)hb;
      lv[j] = (short)f2bf(vv[j] - bf2f(hb));
    }
    *reinterpret_cast<bf16x8*>(&xh[sxr][sxk]) = hv;
    *reinterpret_cast<bf16x8*>(&xl[sxr][sxk]) = lv;
    const ushort* wp = &W1s[kc*8192 + tid*32];
    #pragma unroll
    for (int s=0;s<4;s++)
      *reinterpret_cast<bf16x8*>(&wl[tid][s*8]) =
          *reinterpret_cast<const bf16x8*>(wp + s*8);
    __syncthreads();
    bf16x8 ah[4], al[4];
    #pragma unroll
    for (int rt=0;rt<4;rt++){
      ah[rt] = *reinterpret_cast<const bf16x8*>(&xh[rt*16+l15][lg*8]);
      al[rt] = *reinterpret_cast<const bf16x8*>(&xl[rt*16+l15][lg*8]);
    }
    #pragma unroll
    for (int ct=0;ct<4;ct++){
      bf16x8 bv = *reinterpret_cast<const bf16x8*>(&wl[cb+ct*16+l15][lg*8]);
      #pragma unroll
      for (int rt=0;rt<4;rt++){
        acc[rt][ct] = __builtin_amdgcn_mfma_f32_16x16x32_bf16(al[rt], bv, acc[rt][ct], 0,0,0);
        acc[rt][ct] = __builtin_amdgcn_mfma_f32_16x16x32_bf16(ah[rt], bv, acc[rt][ct], 0,0,0);
      }
    }
  }

  float b1v[4], gv[4], bbv[4];
  #pragma unroll
  for (int ct=0;ct<4;ct++){
    int col = cb + ct*16 + l15;
    b1v[ct] = b1[col]; gv[ct] = g[col]; bbv[ct] = bb[col];
  }
  #pragma unroll
  for (int rt=0;rt<4;rt++)
    #pragma unroll
    for (int ct=0;ct<4;ct++)
      #pragma unroll
      for (int r=0;r<4;r++)
        acc[rt][ct][r] = fmaxf(acc[rt][ct][r] + b1v[ct], 0.f);

  #pragma unroll
  for (int rt=0;rt<4;rt++){
    #pragma unroll
    for (int r=0;r<4;r++){
      float s = acc[rt][0][r]+acc[rt][1][r]+acc[rt][2][r]+acc[rt][3][r];
      float q = acc[rt][0][r]*acc[rt][0][r]+acc[rt][1][r]*acc[rt][1][r]
              + acc[rt][2][r]*acc[rt][2][r]+acc[rt][3][r]*acc[rt][3][r];
      #pragma unroll
      for (int o=1;o<16;o<<=1){ s += __shfl_xor(s,o); q += __shfl_xor(q,o); }
      if (l15 == 0){
        int row = rt*16 + lg*4 + r;
        psum[row][w] = s; psq[row][w] = q;
      }
    }
  }
  __syncthreads();
  if (tid < 64){
    float s = psum[tid][0]+psum[tid][1]+psum[tid][2]+psum[tid][3];
    float q = psq[tid][0]+psq[tid][1]+psq[tid][2]+psq[tid][3];
    float mu  = s * (1.f/256.f);
    float var = q * (1.f/256.f) - mu*mu;
    mub[tid] = mu;
    ivb[tid] = rsqrtf(fmaxf(var, 0.f) + kEps);
  }
  __syncthreads();
  #pragma unroll
  for (int rt=0;rt<4;rt++){
    #pragma unroll
    for (int r=0;r<4;r++){
      int row  = rt*16 + lg*4 + r;
      int grow = n0 + row;
      if (grow < N){
        float mu = mub[row], inv = ivb[row];
        size_t base = (size_t)grow*256 + cb + l15;
        #pragma unroll
        for (int ct=0;ct<4;ct++)
          ego[base + ct*16] = (acc[rt][ct][r]-mu)*inv*gv[ct] + bbv[ct];
      }
    }
  }
}

// ---------------- h = x @ lin_w [256->64] -> bf16 ----------------
__global__ __launch_bounds__(256) void k_hgemm(const float* __restrict__ x,
    const float* __restrict__ W, ushort* __restrict__ h, int N){
  __shared__ float xs[64][72];
  __shared__ float ws[64][64];
  const int tid  = threadIdx.x;
  const int n0   = blockIdx.x * 64;
  const int lane = tid & 63;
  const int m0   = (tid >> 6) * 16;
  const int xn = tid >> 2;        // 0..63
  const int xc = (tid & 3) * 16;  // {0,16,32,48}
  const int wk = tid >> 4;        // 0..15
  const int wj = (tid & 15) * 4;

  float acc[16];
  #pragma unroll
  for (int i=0;i<16;i++) acc[i]=0.f;

  for (int kc=0; kc<4; ++kc){
    int gr = min(n0 + xn, N-1);
    #pragma unroll
    for (int s=0;s<4;s++){
      float4 a = *reinterpret_cast<const float4*>(&x[(size_t)gr*256 + kc*64 + xc + s*4]);
      xs[xc+s*4+0][xn]=a.x; xs[xc+s*4+1][xn]=a.y;
      xs[xc+s*4+2][xn]=a.z; xs[xc+s*4+3][xn]=a.w;
    }
    #pragma unroll
    for (int s=0;s<4;s++){
      int kr = wk + s*16;
      *reinterpret_cast<float4*>(&ws[kr][wj]) =
          *reinterpret_cast<const float4*>(&W[(size_t)(kc*64+kr)*64 + wj]);
    }
    __syncthreads();
    #pragma unroll 8
    for (int k=0;k<64;++k){
      float4 x0 = *reinterpret_cast<const float4*>(&xs[k][m0+ 0]);
      float4 x1 = *reinterpret_cast<const float4*>(&xs[k][m0+ 4]);
      float4 x2 = *reinterpret_cast<const float4*>(&xs[k][m0+ 8]);
      float4 x3 = *reinterpret_cast<const float4*>(&xs[k][m0+12]);
      float wc = ws[k][lane];
      const float xv[16] = {x0.x,x0.y,x0.z,x0.w, x1.x,x1.y,x1.z,x1.w,
                            x2.x,x2.y,x2.z,x2.w, x3.x,x3.y,x3.z,x3.w};
      #pragma unroll
      for (int i=0;i<16;i++) acc[i] = fmaf(xv[i], wc, acc[i]);
    }
    __syncthreads();
  }
  #pragma unroll
  for (int i=0;i<16;i++){
    int m = n0 + m0 + i;
    if (m < N) h[(size_t)m*64 + lane] = f2bf(acc[i]);
  }
}

// ---------------- edge attention, lane = edge (CSR order) ----------------
// Each lane: gather h_row/h_col (bf16, 8x b128 each), compute 4 logits fully
// in registers (attw reads are wave-uniform -> s_load), softmax, store float4.
// rowcsr is sorted -> h_row gathers are quasi-broadcast and L1/L2-hot.
__global__ __launch_bounds__(256) void k_edge(
    const ushort* __restrict__ h,
    const int* __restrict__ rowcsr, const int* __restrict__ colcsr,
    const float* __restrict__ attw,    // [64][4]
    float4* __restrict__ a_csr, int E){
  int e = blockIdx.x*256 + threadIdx.x;
  if (e >= E) return;
  int r = rowcsr[e], c = colcsr[e];
  const uint4* hrp = reinterpret_cast<const uint4*>(h + (size_t)r*64);
  const uint4* hcp = reinterpret_cast<const uint4*>(h + (size_t)c*64);

  float q0=0.f, q1=0.f, q2=0.f, q3=0.f;
  #pragma unroll
  for (int s=0; s<8; ++s){
    uint4 hr4 = hrp[s];
    uint4 hc4 = hcp[s];
    const uint hru[4] = {hr4.x, hr4.y, hr4.z, hr4.w};
    const uint hcu[4] = {hc4.x, hc4.y, hc4.z, hc4.w};
    #pragma unroll
    for (int t=0; t<4; ++t){
      float hrl = __uint_as_float(hru[t]<<16);
      float hrh = __uint_as_float(hru[t]&0xffff0000u);
      float hcl = __uint_as_float(hcu[t]<<16);
      float hch = __uint_as_float(hcu[t]&0xffff0000u);
      float pl = fmaxf(fmaf(0.5f, hrl, hcl), 0.f);
      float ph = fmaxf(fmaf(0.5f, hrh, hch), 0.f);
      int d = s*8 + t*2;
      float4 w0 = *reinterpret_cast<const float4*>(&attw[(d  )*4]);  // uniform
      float4 w1 = *reinterpret_cast<const float4*>(&attw[(d+1)*4]);  // uniform
      q0 = fmaf(pl, w0.x, q0); q1 = fmaf(pl, w0.y, q1);
      q2 = fmaf(pl, w0.z, q2); q3 = fmaf(pl, w0.w, q3);
      q0 = fmaf(ph, w1.x, q0); q1 = fmaf(ph, w1.y, q1);
      q2 = fmaf(ph, w1.z, q2); q3 = fmaf(ph, w1.w, q3);
    }
  }
  float m = fmaxf(fmaxf(q0,q1), fmaxf(q2,q3));
  float e0=__expf(q0-m), e1=__expf(q1-m), e2=__expf(q2-m), e3=__expf(q3-m);
  float inv = 1.f/(e0+e1+e2+e3);
  a_csr[e] = make_float4(e0*inv, e1*inv, e2*inv, e3*inv);
}

// ------- aggregate + relu + LN + residual (attention precomputed) -------
// One wave per node; 4 groups x 16 lanes; group walks every 4th CSR edge.
__global__ __launch_bounds__(256) void k_agg(
    const ushort* __restrict__ h,      // [N][64] bf16
    const int* __restrict__ colcsr, const int* __restrict__ start,
    const float4* __restrict__ a_csr,
    const float* __restrict__ ego,
    const float* __restrict__ g, const float* __restrict__ b,
    float* __restrict__ xout, int N){
  const int lane = threadIdx.x & 63;
  const int grp  = lane >> 4;
  const int l15  = lane & 15;
  const int n = blockIdx.x*4 + (threadIdx.x >> 6);
  if (n >= N) return;

  float acc[4][4];   // [gate][dim j]
  #pragma unroll
  for (int c=0;c<4;c++)
    #pragma unroll
    for (int j=0;j<4;j++) acc[c][j]=0.f;

  const int s0 = start[n], s1 = start[n+1];
  for (int i = s0 + grp; i < s1; i += 4){
    int cn = colcsr[i];
    float4 av = a_csr[i];
    ushort4 hv = *reinterpret_cast<const ushort4*>(&h[(size_t)cn*64 + l15*4]);
    float hc0=bf2f(hv.x), hc1=bf2f(hv.y), hc2=bf2f(hv.z), hc3=bf2f(hv.w);
    acc[0][0]=fmaf(av.x,hc0,acc[0][0]); acc[0][1]=fmaf(av.x,hc1,acc[0][1]);
    acc[0][2]=fmaf(av.x,hc2,acc[0][2]); acc[0][3]=fmaf(av.x,hc3,acc[0][3]);
    acc[1][0]=fmaf(av.y,hc0,acc[1][0]); acc[1][1]=fmaf(av.y,hc1,acc[1][1]);
    acc[1][2]=fmaf(av.y,hc2,acc[1][2]); acc[1][3]=fmaf(av.y,hc3,acc[1][3]);
    acc[2][0]=fmaf(av.z,hc0,acc[2][0]); acc[2][1]=fmaf(av.z,hc1,acc[2][1]);
    acc[2][2]=fmaf(av.z,hc2,acc[2][2]); acc[2][3]=fmaf(av.z,hc3,acc[2][3]);
    acc[3][0]=fmaf(av.w,hc0,acc[3][0]); acc[3][1]=fmaf(av.w,hc1,acc[3][1]);
    acc[3][2]=fmaf(av.w,hc2,acc[3][2]); acc[3][3]=fmaf(av.w,hc3,acc[3][3]);
  }

  // combine the 4 groups (offsets 16,32); then all lanes hold totals
  #pragma unroll
  for (int c=0;c<4;c++)
    #pragma unroll
    for (int j=0;j<4;j++){
      float v = acc[c][j];
      v += __shfl_xor(v,16);
      v += __shfl_xor(v,32);
      acc[c][j] = fmaxf(v, 0.f);   // relu
    }

  // LN stats over 256 cols: per-lane partial of 16 vals, reduce over l15
  float s=0.f, sq=0.f;
  #pragma unroll
  for (int c=0;c<4;c++)
    #pragma unroll
    for (int j=0;j<4;j++){ float v=acc[c][j]; s+=v; sq+=v*v; }
  #pragma unroll
  for (int o=1;o<16;o<<=1){ s += __shfl_xor(s,o); sq += __shfl_xor(sq,o); }
  float mu  = s * (1.f/256.f);
  float var = sq * (1.f/256.f) - mu*mu;
  float inv = rsqrtf(fmaxf(var,0.f) + kEps);

  // group g writes gate g: cols grp*64 + l15*4 .. +3
  int colb = grp*64 + l15*4;
  float4 gv  = *reinterpret_cast<const float4*>(&g[colb]);
  float4 bv  = *reinterpret_cast<const float4*>(&b[colb]);
  size_t base = (size_t)n*256 + colb;
  float4 ev  = *reinterpret_cast<const float4*>(&ego[base]);
  float4 y;
  y.x = (1.f-kBeta)*((acc[grp][0]-mu)*inv*gv.x + bv.x) + kBeta*ev.x;
  y.y = (1.f-kBeta)*((acc[grp][1]-mu)*inv*gv.y + bv.y) + kBeta*ev.y;
  y.z = (1.f-kBeta)*((acc[grp][2]-mu)*inv*gv.z + bv.z) + kBeta*ev.z;
  y.w = (1.f-kBeta)*((acc[grp][3]-mu)*inv*gv.w + bv.w) + kBeta*ev.w;
  *reinterpret_cast<float4*>(&xout[base]) = y;
}

// ---------------- logits = x@W2 + b2 ; log_softmax (fused, tiled) ----------------
__global__ __launch_bounds__(256) void k_out(const float* __restrict__ x,
    const float* __restrict__ W2, const float* __restrict__ b2,
    float* __restrict__ out, int N){
  __shared__ float xs[64][72];
  __shared__ float ws[64][64];
  const int tid  = threadIdx.x;
  const int n0   = blockIdx.x * 64;
  const int lane = tid & 63;
  const int m0   = (tid >> 6) * 16;
  const int xn = tid >> 2;
  const int xc = (tid & 3) * 16;
  const int wk = tid >> 4;
  const int wj = (tid & 15) * 4;

  float acc[16];
  #pragma unroll
  for (int i=0;i<16;i++) acc[i]=0.f;

  for (int kc=0; kc<4; ++kc){
    int gr = min(n0 + xn, N-1);
    #pragma unroll
    for (int s=0;s<4;s++){
      float4 a = *reinterpret_cast<const float4*>(&x[(size_t)gr*256 + kc*64 + xc + s*4]);
      xs[xc+s*4+0][xn]=a.x; xs[xc+s*4+1][xn]=a.y;
      xs[xc+s*4+2][xn]=a.z; xs[xc+s*4+3][xn]=a.w;
    }
    #pragma unroll
    for (int s=0;s<4;s++){
      int kr = wk + s*16;
      *reinterpret_cast<float4*>(&ws[kr][wj]) =
          *reinterpret_cast<const float4*>(&W2[(size_t)(kc*64+kr)*64 + wj]);
    }
    __syncthreads();
    #pragma unroll 8
    for (int k=0;k<64;++k){
      float4 x0 = *reinterpret_cast<const float4*>(&xs[k][m0+ 0]);
      float4 x1 = *reinterpret_cast<const float4*>(&xs[k][m0+ 4]);
      float4 x2 = *reinterpret_cast<const float4*>(&xs[k][m0+ 8]);
      float4 x3 = *reinterpret_cast<const float4*>(&xs[k][m0+12]);
      float wc = ws[k][lane];
      const float xv[16] = {x0.x,x0.y,x0.z,x0.w, x1.x,x1.y,x1.z,x1.w,
                            x2.x,x2.y,x2.z,x2.w, x3.x,x3.y,x3.z,x3.w};
      #pragma unroll
      for (int i=0;i<16;i++) acc[i] = fmaf(xv[i], wc, acc[i]);
    }
    __syncthreads();
  }
  float bias = b2[lane];
  #pragma unroll
  for (int i=0;i<16;i++){
    float l = acc[i] + bias;
    float mx = wredmax(l);
    float sm = wredsum(__expf(l-mx));
    int m = n0 + m0 + i;
    if (m < N) out[(size_t)m*64 + lane] = (l-mx) - __logf(sm);
  }
}

extern "C" void kernel_launch(void* const* d_in, const int* in_sizes, int n_in,
                              void* d_out, int out_size, void* d_ws, size_t ws_size,
                              hipStream_t stream){
  const float* x_in = (const float*)d_in[0];
  const int*   ei   = (const int*)d_in[1];
  const float* W1   = (const float*)d_in[2];
  const float* b1   = (const float*)d_in[3];
  const float* lin  = (const float*)d_in[4];
  const float* att  = (const float*)d_in[5];
  const float* lng  = (const float*)d_in[6];
  const float* lnb  = (const float*)d_in[7];
  const float* W2   = (const float*)d_in[8];
  const float* b2   = (const float*)d_in[9];
  float* out = (float*)d_out;

  const int N = in_sizes[0] / 256;   // 50000
  const int E = in_sizes[1] / 2;     // 800000
  const int* row = ei;
  const int* col = ei + E;

  char* basep = (char*)d_ws;
  size_t off = 0;
  auto alloc = [&](size_t bytes)->char*{
    char* p = basep + off;
    off += (bytes + 255) & ~(size_t)255;
    return p;
  };
  float*  ego    = (float*) alloc((size_t)N*256*4);
  float*  xbuf   = (float*) alloc((size_t)N*256*4);
  ushort* hbuf   = (ushort*)alloc((size_t)N*64*2);
  float4* acsr   = (float4*)alloc((size_t)E*16);
  int*    startp = (int*)   alloc((size_t)(N+1)*4);
  int*    deg    = (int*)   alloc((size_t)N*4);   // also reused as cursor
  int*    rowcsr = (int*)   alloc((size_t)E*4);
  int*    colcsr = (int*)   alloc((size_t)E*4);
  int*    bsum   = (int*)   alloc(256*4);
  int*    boff   = (int*)   alloc(256*4);
  ushort* W1s    = (ushort*)alloc((size_t)256*256*2);

  int nbE = (E + 255)/256;   // 3125
  int nbN = (N + 255)/256;   // 196
  int nbT = (N + 63)/64;     // 782 tiles

  // CSR build
  hipMemsetAsync(deg, 0, (size_t)N*4, stream);
  k_hist<<<nbE,256,0,stream>>>(row, deg, E);
  k_scan_block<<<nbN,256,0,stream>>>(deg, startp, bsum, N);
  k_scan_bsum<<<1,256,0,stream>>>(bsum, boff, nbN);
  k_scan_add<<<nbN,256,0,stream>>>(startp, boff, N);
  hipMemsetAsync(deg, 0, (size_t)N*4, stream);     // cursor
  k_fill<<<nbE,256,0,stream>>>(row, col, startp, deg, rowcsr, colcsr, E);

  // W1 -> bf16 packed; MFMA projection + bias + relu + LN -> ego
  k_prep_w1<<<256,256,0,stream>>>(W1, W1s);
  k_gemm1_mfma<<<nbT,256,0,stream>>>(x_in, W1s, b1, lng, lnb, ego, N);

  for (int L=0; L<2; ++L){
    const float* xsrc = (L == 0) ? ego : xbuf;
    k_hgemm<<<nbT,256,0,stream>>>(xsrc, lin + (size_t)L*256*64, hbuf, N);
    k_edge<<<nbE,256,0,stream>>>(hbuf, rowcsr, colcsr,
                                 att + (size_t)L*64*4, acsr, E);
    k_agg<<<(N+3)/4,256,0,stream>>>(hbuf, colcsr, startp, acsr, ego,
                                    lng + (size_t)(L+1)*256, lnb + (size_t)(L+1)*256,
                                    xbuf, N);
  }
  k_out<<<nbT,256,0,stream>>>(xbuf, W2, b2, out, N);
}